// Round 1
// baseline (2685.635 us; speedup 1.0000x reference)
//
#include <hip/hip_runtime.h>
#include <math.h>

typedef unsigned short u16;
typedef __bf16 bf16x8 __attribute__((ext_vector_type(8)));
typedef float f32x4 __attribute__((ext_vector_type(4)));

// ---------- helpers ----------
__device__ __forceinline__ u16 f2bf(float f){
  unsigned u = __float_as_uint(f);
  unsigned r = u + 0x7fffu + ((u >> 16) & 1u);
  return (u16)(r >> 16);
}
__device__ __forceinline__ float bf2f(u16 h){ return __uint_as_float(((unsigned)h) << 16); }

__device__ __forceinline__ void gload_lds16(const void* g, void* l){
  __builtin_amdgcn_global_load_lds(
      (__attribute__((address_space(1))) void*)(g),
      (__attribute__((address_space(3))) void*)(l), 16, 0, 0);
}
__device__ __forceinline__ f32x4 mfma16(bf16x8 a, bf16x8 b, f32x4 c){
  return __builtin_amdgcn_mfma_f32_16x16x32_bf16(a, b, c, 0, 0, 0);
}
__device__ __forceinline__ float gelu_f(float x){
  float a = 0.7978845608028654f * (x + 0.044715f * x * x * x);
  a = fminf(fmaxf(a, -15.f), 15.f);
  float t = __expf(2.f * a);
  return 0.5f * x * (1.f + (t - 1.f) / (t + 1.f));   // tanh via exp
}

// ---------- transpose + f32->bf16 convert: W[K][N] -> Wt[N][K] ----------
__global__ __launch_bounds__(256) void transcvt(const float* __restrict__ W,
                                                u16* __restrict__ Wt, int K, int N){
  __shared__ float tile[32][33];
  int tx = threadIdx.x & 31, ty = threadIdx.x >> 5;      // 32 x 8
  int n0 = blockIdx.x * 32, k0 = blockIdx.y * 32;
  #pragma unroll
  for (int j = 0; j < 32; j += 8)
    tile[ty + j][tx] = W[(size_t)(k0 + ty + j) * N + n0 + tx];
  __syncthreads();
  #pragma unroll
  for (int j = 0; j < 32; j += 8)
    Wt[(size_t)(n0 + ty + j) * K + k0 + tx] = f2bf(tile[tx][ty + j]);
}

// ---------- embedding + layernorm -> bf16 x ----------
__global__ __launch_bounds__(256) void embed_ln(const int* __restrict__ ids,
    const int* __restrict__ tts, const float* __restrict__ we, const float* __restrict__ pe,
    const float* __restrict__ te, const float* __restrict__ g, const float* __restrict__ bb,
    u16* __restrict__ xb){
  int tok = blockIdx.x * 4 + (threadIdx.x >> 6);
  int lane = threadIdx.x & 63;
  int s = tok & 511;
  int id = ids[tok], tt = tts[tok];
  float e[12]; float sum = 0.f, sq = 0.f;
  #pragma unroll
  for (int j = 0; j < 12; ++j){
    int c = lane + j * 64;
    float v = we[(size_t)id * 768 + c] + pe[(size_t)s * 768 + c] + te[(size_t)tt * 768 + c];
    e[j] = v; sum += v; sq += v * v;
  }
  #pragma unroll
  for (int o = 1; o < 64; o <<= 1){ sum += __shfl_xor(sum, o); sq += __shfl_xor(sq, o); }
  float mean = sum * (1.f / 768.f);
  float var = sq * (1.f / 768.f) - mean * mean;
  float inv = rsqrtf(var + 1e-12f);
  size_t base = (size_t)tok * 768;
  #pragma unroll
  for (int j = 0; j < 12; ++j){
    int c = lane + j * 64;
    xb[base + c] = f2bf((e[j] - mean) * inv * g[c] + bb[c]);
  }
}

// ---------- residual add + layernorm: xout = LN(tmp + res) ----------
__global__ __launch_bounds__(256) void res_ln(const float* __restrict__ tmp,
    const u16* __restrict__ res, const float* __restrict__ g, const float* __restrict__ bb,
    u16* __restrict__ xout){
  int tok = blockIdx.x * 4 + (threadIdx.x >> 6);
  int lane = threadIdx.x & 63;
  size_t base = (size_t)tok * 768;
  float e[12]; float sum = 0.f, sq = 0.f;
  #pragma unroll
  for (int j = 0; j < 12; ++j){
    int c = lane + j * 64;
    float v = tmp[base + c] + bf2f(res[base + c]);
    e[j] = v; sum += v; sq += v * v;
  }
  #pragma unroll
  for (int o = 1; o < 64; o <<= 1){ sum += __shfl_xor(sum, o); sq += __shfl_xor(sq, o); }
  float mean = sum * (1.f / 768.f);
  float var = sq * (1.f / 768.f) - mean * mean;
  float inv = rsqrtf(var + 1e-12f);
  #pragma unroll
  for (int j = 0; j < 12; ++j){
    int c = lane + j * 64;
    xout[base + c] = f2bf((e[j] - mean) * inv * g[c] + bb[c]);
  }
}

// ---------- GEMM: C = A[M][K](bf16) * Bt[N][K]^T (bf16) + bias ----------
// EPI 0: -> bf16 ; 1: gelu -> bf16 ; 2: -> f32
template<int EPI>
__global__ __launch_bounds__(256, 2)
void gemm_bt(const u16* __restrict__ A, const u16* __restrict__ Bt,
             const float* __restrict__ bias, void* __restrict__ Cout,
             int M, int N, int K){
  __shared__ u16 lA[128 * 32];
  __shared__ u16 lB[128 * 32];
  const int tid = threadIdx.x, lane = tid & 63, wv = tid >> 6;
  const int wm = wv >> 1, wn = wv & 1;
  const int row0 = blockIdx.y * 128, col0 = blockIdx.x * 128;
  f32x4 acc[4][4] = {};
  int aoff[4], boff[4];
  #pragma unroll
  for (int m = 0; m < 4; ++m){
    int r = wm * 64 + m * 16 + (lane & 15);
    int p = (lane >> 4) ^ ((r >> 1) & 3);
    aoff[m] = r * 64 + p * 16;
  }
  #pragma unroll
  for (int n = 0; n < 4; ++n){
    int r = wn * 64 + n * 16 + (lane & 15);
    int p = (lane >> 4) ^ ((r >> 1) & 3);
    boff[n] = r * 64 + p * 16;
  }
  for (int k0 = 0; k0 < K; k0 += 32){
    #pragma unroll
    for (int s = 0; s < 2; ++s){
      int i = s * 256 + tid;
      int r = i >> 2, p = i & 3;
      int sk = k0 + ((p ^ ((r >> 1) & 3)) << 3);   // pre-swizzled global source
      gload_lds16(A + (size_t)(row0 + r) * K + sk, (char*)lA + i * 16);
      gload_lds16(Bt + (size_t)(col0 + r) * K + sk, (char*)lB + i * 16);
    }
    __syncthreads();
    bf16x8 af[4], bfv[4];
    #pragma unroll
    for (int m = 0; m < 4; ++m) af[m] = *(const bf16x8*)((const char*)lA + aoff[m]);
    #pragma unroll
    for (int n = 0; n < 4; ++n) bfv[n] = *(const bf16x8*)((const char*)lB + boff[n]);
    #pragma unroll
    for (int m = 0; m < 4; ++m)
      #pragma unroll
      for (int n = 0; n < 4; ++n)
        acc[m][n] = mfma16(af[m], bfv[n], acc[m][n]);
    __syncthreads();
  }
  #pragma unroll
  for (int n = 0; n < 4; ++n){
    int gc = col0 + wn * 64 + n * 16 + (lane & 15);
    float bv = bias[gc];
    #pragma unroll
    for (int m = 0; m < 4; ++m){
      int gr = row0 + wm * 64 + m * 16 + (lane >> 4) * 4;
      #pragma unroll
      for (int j = 0; j < 4; ++j){
        float v = acc[m][n][j] + bv;
        if (EPI == 1) v = gelu_f(v);
        if (EPI == 2) ((float*)Cout)[(size_t)(gr + j) * N + gc] = v;
        else          ((u16*)Cout)[(size_t)(gr + j) * N + gc] = f2bf(v);
      }
    }
  }
}

// ---------- V transpose: qkv v-section -> Vt[bh][d][k] ----------
__global__ __launch_bounds__(256) void vtrans(const u16* __restrict__ qkv, u16* __restrict__ Vt){
  __shared__ u16 t[32][33];
  int bh = blockIdx.z; int b = bh / 12, h = bh % 12;
  int tx = threadIdx.x & 31, ty = threadIdx.x >> 5;
  int k0 = blockIdx.x * 32, d0 = blockIdx.y * 32;
  const u16* src = qkv + (size_t)b * 512 * 2304 + 1536 + (size_t)h * 64;
  #pragma unroll
  for (int j = 0; j < 32; j += 8)
    t[ty + j][tx] = src[(size_t)(k0 + ty + j) * 2304 + d0 + tx];
  __syncthreads();
  u16* dst = Vt + (size_t)bh * 64 * 512;
  #pragma unroll
  for (int j = 0; j < 32; j += 8)
    dst[(size_t)(d0 + ty + j) * 512 + k0 + tx] = t[tx][ty + j];
}

// ---------- attention scores+softmax: P[bh][q][k] (bf16, normalized) ----------
__global__ __launch_bounds__(256, 2) void attn_scores(const u16* __restrict__ qkv,
    const int* __restrict__ amask, u16* __restrict__ P){
  __shared__ u16 lQ[64 * 64];     // swizzled 8-slot rows
  __shared__ u16 lK[128 * 64];    // chunk, swizzled
  __shared__ float lbias[512];
  int q0 = blockIdx.x * 64, h = blockIdx.y, b = blockIdx.z;
  int tid = threadIdx.x, lane = tid & 63, wv = tid >> 6;
  const size_t ld = 2304;
  const u16* base = qkv + (size_t)b * 512 * ld + (size_t)h * 64;
  // stage Q (q0..q0+63, d 0..63)
  #pragma unroll
  for (int s = 0; s < 2; ++s){
    int ii = s * 256 + tid, r = ii >> 3, p = ii & 7;
    gload_lds16(base + (size_t)(q0 + r) * ld + ((p ^ (r & 7)) << 3), (char*)lQ + ii * 16);
  }
  for (int i = tid; i < 512; i += 256)
    lbias[i] = (1.f - (float)amask[(size_t)b * 512 + i]) * -1e9f;
  f32x4 acc[32];
  #pragma unroll
  for (int i = 0; i < 32; ++i) acc[i] = {};
  int mr = wv * 16 + (lane & 15);
  bf16x8 aq[2];
  #pragma unroll
  for (int c = 0; c < 4; ++c){
    #pragma unroll
    for (int s = 0; s < 4; ++s){
      int ii = s * 256 + tid, r = ii >> 3, p = ii & 7;
      gload_lds16(base + 768 + (size_t)(c * 128 + r) * ld + ((p ^ (r & 7)) << 3),
                  (char*)lK + ii * 16);
    }
    __syncthreads();
    if (c == 0){
      #pragma unroll
      for (int ks = 0; ks < 2; ++ks){
        int slog = ks * 4 + (lane >> 4);
        aq[ks] = *(const bf16x8*)((const char*)lQ + mr * 128 + ((slog ^ (mr & 7)) << 4));
      }
    }
    #pragma unroll
    for (int nf = 0; nf < 8; ++nf){
      int kr = nf * 16 + (lane & 15);
      #pragma unroll
      for (int ks = 0; ks < 2; ++ks){
        int slog = ks * 4 + (lane >> 4);
        bf16x8 bk = *(const bf16x8*)((const char*)lK + kr * 128 + ((slog ^ (kr & 7)) << 4));
        acc[c * 8 + nf] = mfma16(aq[ks], bk, acc[c * 8 + nf]);
      }
    }
    __syncthreads();
  }
  // softmax over 512 cols: this wave owns 16 full q-rows
  int cb = lane & 15;
  float mx[4], sm[4];
  #pragma unroll
  for (int j = 0; j < 4; ++j) mx[j] = -3e38f;
  #pragma unroll
  for (int i = 0; i < 32; ++i){
    float bias = lbias[i * 16 + cb];
    #pragma unroll
    for (int j = 0; j < 4; ++j){
      float v = acc[i][j] * 0.125f + bias;
      acc[i][j] = v;
      mx[j] = fmaxf(mx[j], v);
    }
  }
  #pragma unroll
  for (int j = 0; j < 4; ++j){
    #pragma unroll
    for (int o = 1; o < 16; o <<= 1) mx[j] = fmaxf(mx[j], __shfl_xor(mx[j], o));
    sm[j] = 0.f;
  }
  #pragma unroll
  for (int i = 0; i < 32; ++i)
    #pragma unroll
    for (int j = 0; j < 4; ++j){ float p = __expf(acc[i][j] - mx[j]); acc[i][j] = p; sm[j] += p; }
  #pragma unroll
  for (int j = 0; j < 4; ++j){
    #pragma unroll
    for (int o = 1; o < 16; o <<= 1) sm[j] += __shfl_xor(sm[j], o);
    sm[j] = 1.f / sm[j];
  }
  size_t pbase = ((size_t)(b * 12 + h) * 512 + q0 + wv * 16 + (lane >> 4) * 4) * 512;
  #pragma unroll
  for (int i = 0; i < 32; ++i)
    #pragma unroll
    for (int j = 0; j < 4; ++j)
      P[pbase + (size_t)j * 512 + i * 16 + cb] = f2bf(acc[i][j] * sm[j]);
}

// ---------- PV: ctx[q][h*64+d] = P[bh] @ V[bh] ----------
__global__ __launch_bounds__(256, 2) void attn_pv(const u16* __restrict__ P,
    const u16* __restrict__ Vt, u16* __restrict__ ctx){
  __shared__ u16 lP[128 * 32];
  __shared__ u16 lV[64 * 32];
  int bh = blockIdx.y; int b = bh / 12, h = bh % 12;
  int q0 = blockIdx.x * 128;
  int tid = threadIdx.x, lane = tid & 63, wv = tid >> 6, wm = wv >> 1, wn = wv & 1;
  const u16* Pg = P + ((size_t)bh * 512 + q0) * 512;
  const u16* Vg = Vt + (size_t)bh * 64 * 512;
  f32x4 acc[4][2] = {};
  int aoff[4], boff[2];
  #pragma unroll
  for (int m = 0; m < 4; ++m){
    int r = wm * 64 + m * 16 + (lane & 15);
    int p = (lane >> 4) ^ ((r >> 1) & 3);
    aoff[m] = r * 64 + p * 16;
  }
  #pragma unroll
  for (int n = 0; n < 2; ++n){
    int r = wn * 32 + n * 16 + (lane & 15);
    int p = (lane >> 4) ^ ((r >> 1) & 3);
    boff[n] = r * 64 + p * 16;
  }
  for (int k0 = 0; k0 < 512; k0 += 32){
    #pragma unroll
    for (int s = 0; s < 2; ++s){
      int i = s * 256 + tid, r = i >> 2, p = i & 3;
      gload_lds16(Pg + (size_t)r * 512 + k0 + ((p ^ ((r >> 1) & 3)) << 3), (char*)lP + i * 16);
    }
    { int r = tid >> 2, p = tid & 3;
      gload_lds16(Vg + (size_t)r * 512 + k0 + ((p ^ ((r >> 1) & 3)) << 3), (char*)lV + tid * 16); }
    __syncthreads();
    bf16x8 af[4], bv[2];
    #pragma unroll
    for (int m = 0; m < 4; ++m) af[m] = *(const bf16x8*)((const char*)lP + aoff[m]);
    #pragma unroll
    for (int n = 0; n < 2; ++n) bv[n] = *(const bf16x8*)((const char*)lV + boff[n]);
    #pragma unroll
    for (int m = 0; m < 4; ++m)
      #pragma unroll
      for (int n = 0; n < 2; ++n)
        acc[m][n] = mfma16(af[m], bv[n], acc[m][n]);
    __syncthreads();
  }
  u16* C = ctx + (size_t)b * 512 * 768 + (size_t)h * 64;
  #pragma unroll
  for (int m = 0; m < 4; ++m)
    #pragma unroll
    for (int n = 0; n < 2; ++n){
      int d = wn * 32 + n * 16 + (lane & 15);
      int qr = q0 + wm * 64 + m * 16 + (lane >> 4) * 4;
      #pragma unroll
      for (int j = 0; j < 4; ++j)
        C[(size_t)(qr + j) * 768 + d] = f2bf(acc[m][n][j]);
    }
}

// ---------- emissions: x @ Wt(768x9 f32) + bt -> f32 ----------
__global__ __launch_bounds__(256) void emis_k(const u16* __restrict__ xb,
    const float* __restrict__ Wt, const float* __restrict__ bt, float* __restrict__ emis){
  int row = blockIdx.x * 4 + (threadIdx.x >> 6);
  int lane = threadIdx.x & 63;
  float a[9] = {};
  #pragma unroll
  for (int j = 0; j < 12; ++j){
    int k = lane + j * 64;
    float xv = bf2f(xb[(size_t)row * 768 + k]);
    #pragma unroll
    for (int t = 0; t < 9; ++t) a[t] += xv * Wt[(size_t)k * 9 + t];
  }
  #pragma unroll
  for (int o = 1; o < 64; o <<= 1)
    #pragma unroll
    for (int t = 0; t < 9; ++t) a[t] += __shfl_xor(a[t], o);
  if (lane == 0){
    #pragma unroll
    for (int t = 0; t < 9; ++t) emis[(size_t)row * 9 + t] = a[t] + bt[t];
  }
}

// ---------- CRF NLL ----------
__global__ __launch_bounds__(128) void crf_k(const float* __restrict__ emis,
    const int* __restrict__ labels, const int* __restrict__ amask,
    const float* __restrict__ cstart, const float* __restrict__ cend,
    const float* __restrict__ ctrans, float* __restrict__ out){
  __shared__ float numb[8], denb[8];
  int tid = threadIdx.x;
  { // ---- numerator (parallel reduction), 16 threads per batch ----
    int b = tid >> 4, g = tid & 15;
    const int* lab = labels + (size_t)b * 512;
    const int* msk = amask + (size_t)b * 512;
    float part = 0.f; int cnt = 0;
    for (int i = g; i < 512; i += 16){
      int m = msk[i]; cnt += m;
      if (i >= 1){
        int tp = lab[i - 1], tc = lab[i];
        part += (ctrans[tp * 9 + tc] + emis[((size_t)b * 512 + i) * 9 + tc]) * (float)m;
      }
    }
    #pragma unroll
    for (int o = 1; o < 16; o <<= 1){ part += __shfl_xor(part, o); cnt += __shfl_xor(cnt, o); }
    if (g == 0){
      int t0 = lab[0];
      numb[b] = part + cstart[t0] + emis[((size_t)b * 512) * 9 + t0] + cend[lab[cnt - 1]];
    }
  }
  __syncthreads();
  { // ---- denominator: forward algorithm, tags in lanes, no barriers ----
    int w = tid >> 6, lane = tid & 63;
    int sub = lane / 9;
    int t = lane - sub * 9;
    bool act = (sub < 4) && (lane < 36);
    int b = w * 4 + (act ? sub : 0);
    int sb = act ? sub : 0;
    float tr[9];
    #pragma unroll
    for (int i = 0; i < 9; ++i) tr[i] = ctrans[i * 9 + t];
    const float* eb = emis + (size_t)b * 512 * 9;
    const int* mb = amask + (size_t)b * 512;
    float alpha = cstart[t] + eb[t];
    float e_c = eb[9 + t], e_n = eb[18 + t];
    int m_c = mb[1], m_n = mb[2];
    for (int i = 1; i < 512; ++i){
      int ipre = (i + 2 <= 511) ? i + 2 : 511;
      float e_t = eb[(size_t)ipre * 9 + t];
      int m_t = mb[ipre];
      float av[9];
      #pragma unroll
      for (int ii = 0; ii < 9; ++ii) av[ii] = __shfl(alpha, sb * 9 + ii);
      float mm = -3e38f;
      #pragma unroll
      for (int ii = 0; ii < 9; ++ii){ av[ii] += tr[ii]; mm = fmaxf(mm, av[ii]); }
      float ss = 0.f;
      #pragma unroll
      for (int ii = 0; ii < 9; ++ii) ss += __expf(av[ii] - mm);
      float nxt = mm + __logf(ss) + e_c;
      alpha = m_c ? nxt : alpha;
      e_c = e_n; e_n = e_t; m_c = m_n; m_n = m_t;
    }
    float v = alpha + cend[t];
    float av[9];
    #pragma unroll
    for (int ii = 0; ii < 9; ++ii) av[ii] = __shfl(v, sb * 9 + ii);
    float mm = -3e38f;
    #pragma unroll
    for (int ii = 0; ii < 9; ++ii) mm = fmaxf(mm, av[ii]);
    float ss = 0.f;
    #pragma unroll
    for (int ii = 0; ii < 9; ++ii) ss += __expf(av[ii] - mm);
    if (act && t == 0) denb[b] = mm + __logf(ss);
  }
  __syncthreads();
  if (tid == 0){
    float s = 0.f;
    #pragma unroll
    for (int b = 0; b < 8; ++b) s += numb[b] - denb[b];
    out[0] = -(s * 0.125f);
  }
}

// ---------- host ----------
extern "C" void kernel_launch(void* const* d_in, const int* in_sizes, int n_in,
                              void* d_out, int out_size, void* d_ws, size_t ws_size,
                              hipStream_t stream){
  const int*   input_ids = (const int*)d_in[0];
  const int*   amask     = (const int*)d_in[1];
  const int*   ttids     = (const int*)d_in[2];
  const int*   labels    = (const int*)d_in[3];
  const float* word_emb  = (const float*)d_in[4];
  const float* pos_emb   = (const float*)d_in[5];
  const float* type_emb  = (const float*)d_in[6];
  const float* eln_s     = (const float*)d_in[7];
  const float* eln_b     = (const float*)d_in[8];
  const float* Wqkv      = (const float*)d_in[9];
  const float* bqkv      = (const float*)d_in[10];
  const float* Wo        = (const float*)d_in[11];
  const float* bo        = (const float*)d_in[12];
  const float* ln1s      = (const float*)d_in[13];
  const float* ln1b      = (const float*)d_in[14];
  const float* W1        = (const float*)d_in[15];
  const float* b1        = (const float*)d_in[16];
  const float* W2        = (const float*)d_in[17];
  const float* b2        = (const float*)d_in[18];
  const float* ln2s      = (const float*)d_in[19];
  const float* ln2b      = (const float*)d_in[20];
  const float* Wt        = (const float*)d_in[21];
  const float* bt        = (const float*)d_in[22];
  const float* cstart    = (const float*)d_in[23];
  const float* cend      = (const float*)d_in[24];
  const float* ctrans    = (const float*)d_in[25];

  char* w = (char*)d_ws;
  auto alloc = [&](size_t sz){ char* p = w; w += (sz + 255) & ~(size_t)255; return p; };
  u16*   xb     = (u16*)  alloc(4096ULL * 768 * 2);
  u16*   qkvb   = (u16*)  alloc(4096ULL * 2304 * 2);
  u16*   ctxb   = (u16*)  alloc(4096ULL * 768 * 2);
  float* tmp    = (float*)alloc(4096ULL * 768 * 4);
  u16*   hb     = (u16*)  alloc(4096ULL * 3072 * 2);
  u16*   Pb     = (u16*)  alloc(96ULL * 512 * 512 * 2);
  u16*   Vtb    = (u16*)  alloc(96ULL * 64 * 512 * 2);
  u16*   Wqkv_b = (u16*)  alloc(2304ULL * 768 * 2);
  u16*   Wo_b   = (u16*)  alloc(768ULL * 768 * 2);
  u16*   W1_b   = (u16*)  alloc(3072ULL * 768 * 2);
  u16*   W2_b   = (u16*)  alloc(768ULL * 3072 * 2);
  float* emis   = (float*)alloc(8ULL * 512 * 9 * 4);
  (void)ws_size; (void)in_sizes; (void)n_in; (void)out_size;

  embed_ln<<<1024, 256, 0, stream>>>(input_ids, ttids, word_emb, pos_emb, type_emb,
                                     eln_s, eln_b, xb);
  for (int l = 0; l < 12; ++l){
    transcvt<<<dim3(72, 24), 256, 0, stream>>>(Wqkv + (size_t)l * 768 * 2304, Wqkv_b, 768, 2304);
    gemm_bt<0><<<dim3(18, 32), 256, 0, stream>>>(xb, Wqkv_b, bqkv + (size_t)l * 2304, qkvb,
                                                 4096, 2304, 768);
    vtrans<<<dim3(16, 2, 96), 256, 0, stream>>>(qkvb, Vtb);
    attn_scores<<<dim3(8, 12, 8), 256, 0, stream>>>(qkvb, amask, Pb);
    attn_pv<<<dim3(4, 96), 256, 0, stream>>>(Pb, Vtb, ctxb);
    transcvt<<<dim3(24, 24), 256, 0, stream>>>(Wo + (size_t)l * 768 * 768, Wo_b, 768, 768);
    gemm_bt<2><<<dim3(6, 32), 256, 0, stream>>>(ctxb, Wo_b, bo + (size_t)l * 768, tmp,
                                                4096, 768, 768);
    res_ln<<<1024, 256, 0, stream>>>(tmp, xb, ln1s + (size_t)l * 768, ln1b + (size_t)l * 768, xb);
    transcvt<<<dim3(96, 24), 256, 0, stream>>>(W1 + (size_t)l * 768 * 3072, W1_b, 768, 3072);
    gemm_bt<1><<<dim3(24, 32), 256, 0, stream>>>(xb, W1_b, b1 + (size_t)l * 3072, hb,
                                                 4096, 3072, 768);
    transcvt<<<dim3(24, 96), 256, 0, stream>>>(W2 + (size_t)l * 3072 * 768, W2_b, 3072, 768);
    gemm_bt<2><<<dim3(6, 32), 256, 0, stream>>>(hb, W2_b, b2 + (size_t)l * 768, tmp,
                                                4096, 768, 3072);
    res_ln<<<1024, 256, 0, stream>>>(tmp, xb, ln2s + (size_t)l * 768, ln2b + (size_t)l * 768, xb);
  }
  emis_k<<<1024, 256, 0, stream>>>(xb, Wt, bt, emis);
  crf_k<<<1, 128, 0, stream>>>(emis, labels, amask, cstart, cend, ctrans, (float*)d_out);
}

// Round 2
// 2404.960 us; speedup vs baseline: 1.1167x; 1.1167x over previous
//
#include <hip/hip_runtime.h>
#include <math.h>

typedef unsigned short u16;
typedef unsigned int u32;
typedef __bf16 bf16x8 __attribute__((ext_vector_type(8)));
typedef float f32x4 __attribute__((ext_vector_type(4)));

// ---------- helpers ----------
__device__ __forceinline__ u16 f2bf(float f){
  unsigned u = __float_as_uint(f);
  unsigned r = u + 0x7fffu + ((u >> 16) & 1u);
  return (u16)(r >> 16);
}
__device__ __forceinline__ float bf2f(u16 h){ return __uint_as_float(((unsigned)h) << 16); }

__device__ __forceinline__ void gload_lds16(const void* g, void* l){
  __builtin_amdgcn_global_load_lds(
      (__attribute__((address_space(1))) void*)(g),
      (__attribute__((address_space(3))) void*)(l), 16, 0, 0);
}
__device__ __forceinline__ f32x4 mfma16(bf16x8 a, bf16x8 b, f32x4 c){
  return __builtin_amdgcn_mfma_f32_16x16x32_bf16(a, b, c, 0, 0, 0);
}
__device__ __forceinline__ float gelu_f(float x){
  float a = 0.7978845608028654f * (x + 0.044715f * x * x * x);
  a = fminf(fmaxf(a, -15.f), 15.f);
  float t = __expf(2.f * a);
  return 0.5f * x * (1.f + (t - 1.f) / (t + 1.f));
}

// ---------- transpose + f32->bf16 convert: W[K][N] -> Wt[N][K] ----------
__global__ __launch_bounds__(256) void transcvt(const float* __restrict__ W,
                                                u16* __restrict__ Wt, int K, int N){
  __shared__ float tile[32][33];
  int tx = threadIdx.x & 31, ty = threadIdx.x >> 5;
  int n0 = blockIdx.x * 32, k0 = blockIdx.y * 32;
  #pragma unroll
  for (int j = 0; j < 32; j += 8)
    tile[ty + j][tx] = W[(size_t)(k0 + ty + j) * N + n0 + tx];
  __syncthreads();
  #pragma unroll
  for (int j = 0; j < 32; j += 8)
    Wt[(size_t)(n0 + ty + j) * K + k0 + tx] = f2bf(tile[tx][ty + j]);
}

// ---------- embedding + layernorm -> bf16 x ----------
__global__ __launch_bounds__(256) void embed_ln(const int* __restrict__ ids,
    const int* __restrict__ tts, const float* __restrict__ we, const float* __restrict__ pe,
    const float* __restrict__ te, const float* __restrict__ g, const float* __restrict__ bb,
    u16* __restrict__ xb){
  int tok = blockIdx.x * 4 + (threadIdx.x >> 6);
  int lane = threadIdx.x & 63;
  int s = tok & 511;
  int id = ids[tok], tt = tts[tok];
  float e[12]; float sum = 0.f, sq = 0.f;
  #pragma unroll
  for (int j = 0; j < 12; ++j){
    int c = lane + j * 64;
    float v = we[(size_t)id * 768 + c] + pe[(size_t)s * 768 + c] + te[(size_t)tt * 768 + c];
    e[j] = v; sum += v; sq += v * v;
  }
  #pragma unroll
  for (int o = 1; o < 64; o <<= 1){ sum += __shfl_xor(sum, o); sq += __shfl_xor(sq, o); }
  float mean = sum * (1.f / 768.f);
  float var = sq * (1.f / 768.f) - mean * mean;
  float inv = rsqrtf(var + 1e-12f);
  size_t base = (size_t)tok * 768;
  #pragma unroll
  for (int j = 0; j < 12; ++j){
    int c = lane + j * 64;
    xb[base + c] = f2bf((e[j] - mean) * inv * g[c] + bb[c]);
  }
}

// ---------- residual add + layernorm (both bf16, vectorized) ----------
__global__ __launch_bounds__(256) void res_ln(const u16* __restrict__ tmp,
    const u16* __restrict__ res, const float* __restrict__ g, const float* __restrict__ bb,
    u16* __restrict__ xout){
  int tok = blockIdx.x * 4 + (threadIdx.x >> 6);
  int lane = threadIdx.x & 63;
  size_t base = (size_t)tok * 768;
  float v[12]; float sum = 0.f, sq = 0.f;
  #pragma unroll
  for (int j = 0; j < 3; ++j){
    int c = j * 256 + lane * 4;
    ushort4 a = *(const ushort4*)(tmp + base + c);
    ushort4 r = *(const ushort4*)(res + base + c);
    const u16* ap = (const u16*)&a; const u16* rp = (const u16*)&r;
    #pragma unroll
    for (int e = 0; e < 4; ++e){
      float f = bf2f(ap[e]) + bf2f(rp[e]);
      v[j * 4 + e] = f; sum += f; sq += f * f;
    }
  }
  #pragma unroll
  for (int o = 1; o < 64; o <<= 1){ sum += __shfl_xor(sum, o); sq += __shfl_xor(sq, o); }
  float mean = sum * (1.f / 768.f);
  float var = sq * (1.f / 768.f) - mean * mean;
  float inv = rsqrtf(var + 1e-12f);
  #pragma unroll
  for (int j = 0; j < 3; ++j){
    int c = j * 256 + lane * 4;
    f32x4 gs = *(const f32x4*)(g + c);
    f32x4 bs = *(const f32x4*)(bb + c);
    ushort4 o; u16* op = (u16*)&o;
    #pragma unroll
    for (int e = 0; e < 4; ++e)
      op[e] = f2bf((v[j * 4 + e] - mean) * inv * gs[e] + bs[e]);
    *(ushort4*)(xout + base + c) = o;
  }
}

// ---------- GEMM: C = A[M][K](bf16) * Bt[N][K]^T (bf16) + bias ----------
// EPI 0: -> bf16 ; 1: gelu -> bf16
template<int EPI>
__global__ __launch_bounds__(256, 2)
void gemm_bt(const u16* __restrict__ A, const u16* __restrict__ Bt,
             const float* __restrict__ bias, void* __restrict__ Cout,
             int M, int N, int K){
  __shared__ u16 lA[128 * 32];
  __shared__ u16 lB[128 * 32];
  const int tid = threadIdx.x, lane = tid & 63, wv = tid >> 6;
  const int wm = wv >> 1, wn = wv & 1;
  const int row0 = blockIdx.y * 128, col0 = blockIdx.x * 128;
  f32x4 acc[4][4] = {};
  int aoff[4], boff[4];
  #pragma unroll
  for (int m = 0; m < 4; ++m){
    int r = wm * 64 + m * 16 + (lane & 15);
    int p = (lane >> 4) ^ ((r >> 1) & 3);
    aoff[m] = r * 64 + p * 16;
  }
  #pragma unroll
  for (int n = 0; n < 4; ++n){
    int r = wn * 64 + n * 16 + (lane & 15);
    int p = (lane >> 4) ^ ((r >> 1) & 3);
    boff[n] = r * 64 + p * 16;
  }
  for (int k0 = 0; k0 < K; k0 += 32){
    #pragma unroll
    for (int s = 0; s < 2; ++s){
      int i = s * 256 + tid;
      int r = i >> 2, p = i & 3;
      int sk = k0 + ((p ^ ((r >> 1) & 3)) << 3);
      gload_lds16(A + (size_t)(row0 + r) * K + sk, (char*)lA + i * 16);
      gload_lds16(Bt + (size_t)(col0 + r) * K + sk, (char*)lB + i * 16);
    }
    __syncthreads();
    bf16x8 af[4], bfv[4];
    #pragma unroll
    for (int m = 0; m < 4; ++m) af[m] = *(const bf16x8*)((const char*)lA + aoff[m]);
    #pragma unroll
    for (int n = 0; n < 4; ++n) bfv[n] = *(const bf16x8*)((const char*)lB + boff[n]);
    #pragma unroll
    for (int m = 0; m < 4; ++m)
      #pragma unroll
      for (int n = 0; n < 4; ++n)
        acc[m][n] = mfma16(af[m], bfv[n], acc[m][n]);
    __syncthreads();
  }
  #pragma unroll
  for (int n = 0; n < 4; ++n){
    int gc = col0 + wn * 64 + n * 16 + (lane & 15);
    float bv = bias[gc];
    #pragma unroll
    for (int m = 0; m < 4; ++m){
      int gr = row0 + wm * 64 + m * 16 + (lane >> 4) * 4;
      #pragma unroll
      for (int j = 0; j < 4; ++j){
        float v = acc[m][n][j] + bv;
        if (EPI == 1) v = gelu_f(v);
        ((u16*)Cout)[(size_t)(gr + j) * N + gc] = f2bf(v);
      }
    }
  }
}

// ---------- V transpose: qkv v-section -> Vt[bh][d][k] ----------
__global__ __launch_bounds__(256) void vtrans(const u16* __restrict__ qkv, u16* __restrict__ Vt){
  __shared__ u16 t[32][33];
  int bh = blockIdx.z; int b = bh / 12, h = bh % 12;
  int tx = threadIdx.x & 31, ty = threadIdx.x >> 5;
  int k0 = blockIdx.x * 32, d0 = blockIdx.y * 32;
  const u16* src = qkv + (size_t)b * 512 * 2304 + 1536 + (size_t)h * 64;
  #pragma unroll
  for (int j = 0; j < 32; j += 8)
    t[ty + j][tx] = src[(size_t)(k0 + ty + j) * 2304 + d0 + tx];
  __syncthreads();
  u16* dst = Vt + (size_t)bh * 64 * 512;
  #pragma unroll
  for (int j = 0; j < 32; j += 8)
    dst[(size_t)(d0 + ty + j) * 512 + k0 + tx] = t[tx][ty + j];
}

// ---------- fused attention: S^T = K·Q^T, per-lane softmax, PV ----------
__global__ __launch_bounds__(256, 2) void attn_fused(const u16* __restrict__ qkv,
    const int* __restrict__ amask, const u16* __restrict__ Vt, u16* __restrict__ ctx){
  __shared__ u16 lQ[64 * 64];
  __shared__ u16 lK[128 * 64];   // scores phase: K chunk; PV phase: per-wave P buffers
  __shared__ u16 lV[64 * 128];
  __shared__ float lbias[512];
  int q0 = blockIdx.x * 64, h = blockIdx.y, b = blockIdx.z;
  int tid = threadIdx.x, lane = tid & 63, wv = tid >> 6;
  int q15 = lane & 15, g = lane >> 4;
  const size_t ld = 2304;
  const u16* base = qkv + (size_t)b * 512 * ld + (size_t)h * 64;
  #pragma unroll
  for (int s = 0; s < 2; ++s){
    int ii = s * 256 + tid, r = ii >> 3, p = ii & 7;
    gload_lds16(base + (size_t)(q0 + r) * ld + ((p ^ (r & 7)) << 3), (char*)lQ + ii * 16);
  }
  for (int i = tid; i < 512; i += 256)
    lbias[i] = (1.f - (float)amask[(size_t)b * 512 + i]) * -1e9f;
  f32x4 acc[32];
  #pragma unroll
  for (int i = 0; i < 32; ++i) acc[i] = {};
  int mr = wv * 16 + q15;
  bf16x8 aq[2];
  #pragma unroll
  for (int c = 0; c < 4; ++c){
    #pragma unroll
    for (int s = 0; s < 4; ++s){
      int ii = s * 256 + tid, r = ii >> 3, p = ii & 7;
      gload_lds16(base + 768 + (size_t)(c * 128 + r) * ld + ((p ^ (r & 7)) << 3),
                  (char*)lK + ii * 16);
    }
    __syncthreads();
    if (c == 0){
      #pragma unroll
      for (int ks = 0; ks < 2; ++ks){
        int slog = ks * 4 + g;
        aq[ks] = *(const bf16x8*)((const char*)lQ + mr * 128 + ((slog ^ (mr & 7)) << 4));
      }
    }
    #pragma unroll
    for (int nf = 0; nf < 8; ++nf){
      int kr = nf * 16 + q15;
      #pragma unroll
      for (int ks = 0; ks < 2; ++ks){
        int slog = ks * 4 + g;
        bf16x8 bk = *(const bf16x8*)((const char*)lK + kr * 128 + ((slog ^ (kr & 7)) << 4));
        acc[c * 8 + nf] = mfma16(bk, aq[ks], acc[c * 8 + nf]);   // C[k][q]
      }
    }
    __syncthreads();
  }
  // per-lane softmax: lane owns q = q0+wv*16+q15, k = i*16 + g*4 + j
  float mx = -3e38f;
  #pragma unroll
  for (int i = 0; i < 32; ++i){
    f32x4 b4 = *(const f32x4*)((const char*)lbias + i * 64 + g * 16);
    #pragma unroll
    for (int j = 0; j < 4; ++j){
      float v = acc[i][j] * 0.125f + b4[j];
      acc[i][j] = v; mx = fmaxf(mx, v);
    }
  }
  mx = fmaxf(mx, __shfl_xor(mx, 16));
  mx = fmaxf(mx, __shfl_xor(mx, 32));
  float sm = 0.f;
  #pragma unroll
  for (int i = 0; i < 32; ++i)
    #pragma unroll
    for (int j = 0; j < 4; ++j){ float p = __expf(acc[i][j] - mx); acc[i][j] = p; sm += p; }
  sm += __shfl_xor(sm, 16);
  sm += __shfl_xor(sm, 32);
  float inv = 1.f / sm;
  // PV
  const u16* Vg = Vt + (size_t)(b * 12 + h) * 64 * 512;
  f32x4 accpv[4] = {};
  char* wvP = (char*)lK + wv * 4096;   // per-wave 16q x 128k bf16, XOR-swizzled
  #pragma unroll
  for (int c = 0; c < 4; ++c){
    #pragma unroll
    for (int s = 0; s < 4; ++s){
      int ii = s * 256 + tid, r = ii >> 4, p = ii & 15;
      gload_lds16(Vg + (size_t)r * 512 + c * 128 + ((p ^ (r & 7)) << 3), (char*)lV + ii * 16);
    }
    #pragma unroll
    for (int i2 = 0; i2 < 8; ++i2){
      int i = c * 8 + i2;
      u32 w0 = (u32)f2bf(acc[i][0] * inv) | ((u32)f2bf(acc[i][1] * inv) << 16);
      u32 w1 = (u32)f2bf(acc[i][2] * inv) | ((u32)f2bf(acc[i][3] * inv) << 16);
      int slot = i2 * 2 + (g >> 1);
      char* ad = wvP + q15 * 256 + ((slot ^ (q15 & 7)) << 4) + ((g & 1) << 3);
      *(uint2*)ad = uint2{w0, w1};
    }
    __syncthreads();
    #pragma unroll
    for (int s = 0; s < 4; ++s){
      bf16x8 pa = *(const bf16x8*)(wvP + q15 * 256 + (((s * 4 + g) ^ (q15 & 7)) << 4));
      #pragma unroll
      for (int nf = 0; nf < 4; ++nf){
        int dr = nf * 16 + q15;
        bf16x8 bv = *(const bf16x8*)((const char*)lV + dr * 256 + (((s * 4 + g) ^ (dr & 7)) << 4));
        accpv[nf] = mfma16(pa, bv, accpv[nf]);
      }
    }
    __syncthreads();
  }
  u16* C = ctx + (size_t)b * 512 * 768 + (size_t)h * 64;
  #pragma unroll
  for (int nf = 0; nf < 4; ++nf)
    #pragma unroll
    for (int j = 0; j < 4; ++j){
      int q = q0 + wv * 16 + g * 4 + j;
      int d = nf * 16 + q15;
      C[(size_t)q * 768 + d] = f2bf(accpv[nf][j]);
    }
}

// ---------- emissions: x @ Wt(768x9 f32) + bt -> f32 ----------
__global__ __launch_bounds__(256) void emis_k(const u16* __restrict__ xb,
    const float* __restrict__ Wt, const float* __restrict__ bt, float* __restrict__ emis){
  int row = blockIdx.x * 4 + (threadIdx.x >> 6);
  int lane = threadIdx.x & 63;
  float a[9] = {};
  #pragma unroll
  for (int j = 0; j < 12; ++j){
    int k = lane + j * 64;
    float xv = bf2f(xb[(size_t)row * 768 + k]);
    #pragma unroll
    for (int t = 0; t < 9; ++t) a[t] += xv * Wt[(size_t)k * 9 + t];
  }
  #pragma unroll
  for (int o = 1; o < 64; o <<= 1)
    #pragma unroll
    for (int t = 0; t < 9; ++t) a[t] += __shfl_xor(a[t], o);
  if (lane == 0){
    #pragma unroll
    for (int t = 0; t < 9; ++t) emis[(size_t)row * 9 + t] = a[t] + bt[t];
  }
}

// ---------- CRF chunk products: log-semiring 9x9 matrix scan ----------
// chunk c covers t in [c*32 (+1 if c==0), c*32+31]; 16 chunks x 8 batches
__global__ __launch_bounds__(128) void crf_chunk(const float* __restrict__ emis,
    const int* __restrict__ amask, const float* __restrict__ ctrans,
    float* __restrict__ chunkP){
  __shared__ float cur[2][96];
  int blk = blockIdx.x; int b = blk >> 4, c = blk & 15;
  int t0 = threadIdx.x;
  bool act = t0 < 81;
  int tc = act ? t0 : 0;
  int i = tc / 9, j = tc - i * 9;
  float tr[9];
  #pragma unroll
  for (int k = 0; k < 9; ++k) tr[k] = ctrans[k * 9 + j];
  const float* eb = emis + (size_t)b * 512 * 9;
  const int* mb = amask + (size_t)b * 512;
  int lo = c * 32 + (c == 0 ? 1 : 0), hi = c * 32 + 31;
  if (act){
    int m = mb[lo];
    cur[0][t0] = m ? (ctrans[i * 9 + j] + eb[(size_t)lo * 9 + j])
                   : (i == j ? 0.f : -1e30f);
  }
  __syncthreads();
  int pp = 0;
  for (int t = lo + 1; t <= hi; ++t){
    float a[9];
    #pragma unroll
    for (int k = 0; k < 9; ++k) a[k] = cur[pp][i * 9 + k];
    int m = mb[t];
    float outv;
    if (m){
      float ej = eb[(size_t)t * 9 + j];
      float mm = -3e38f;
      #pragma unroll
      for (int k = 0; k < 9; ++k){ a[k] += tr[k]; mm = fmaxf(mm, a[k]); }
      float ss = 0.f;
      #pragma unroll
      for (int k = 0; k < 9; ++k) ss += __expf(a[k] - mm);
      outv = ej + mm + __logf(ss);
    } else {
      outv = a[j];
    }
    if (act) cur[pp ^ 1][t0] = outv;
    __syncthreads();
    pp ^= 1;
  }
  if (act) chunkP[(size_t)(b * 16 + c) * 81 + t0] = cur[pp][t0];
}

// ---------- CRF final: numerator + apply chunk products + combine ----------
__global__ __launch_bounds__(128) void crf_final(const float* __restrict__ emis,
    const int* __restrict__ labels, const int* __restrict__ amask,
    const float* __restrict__ cstart, const float* __restrict__ cend,
    const float* __restrict__ ctrans, const float* __restrict__ chunkP,
    float* __restrict__ out){
  __shared__ float numb[8], denb[8];
  int tid = threadIdx.x;
  { // numerator
    int b = tid >> 4, gg = tid & 15;
    const int* lab = labels + (size_t)b * 512;
    const int* msk = amask + (size_t)b * 512;
    float part = 0.f; int cnt = 0;
    for (int i = gg; i < 512; i += 16){
      int m = msk[i]; cnt += m;
      if (i >= 1){
        int tp = lab[i - 1], tcc = lab[i];
        part += (ctrans[tp * 9 + tcc] + emis[((size_t)b * 512 + i) * 9 + tcc]) * (float)m;
      }
    }
    #pragma unroll
    for (int o = 1; o < 16; o <<= 1){ part += __shfl_xor(part, o); cnt += __shfl_xor(cnt, o); }
    if (gg == 0){
      int tt0 = lab[0];
      numb[b] = part + cstart[tt0] + emis[((size_t)b * 512) * 9 + tt0] + cend[lab[cnt - 1]];
    }
  }
  __syncthreads();
  { // denominator via 16 chunk products
    int lane = tid & 63, w = tid >> 6;
    int sub = lane >> 4, j = lane & 15;
    int b = w * 4 + sub;
    bool act = j < 9;
    int jj = act ? j : 0;
    int gbase = lane & 48;
    float alpha = cstart[jj] + emis[(size_t)b * 512 * 9 + jj];
    for (int c = 0; c < 16; ++c){
      const float* P = chunkP + (size_t)(b * 16 + c) * 81;
      float av[9];
      #pragma unroll
      for (int k = 0; k < 9; ++k) av[k] = __shfl(alpha, gbase + k) + P[k * 9 + jj];
      float mm = -3e38f;
      #pragma unroll
      for (int k = 0; k < 9; ++k) mm = fmaxf(mm, av[k]);
      float ss = 0.f;
      #pragma unroll
      for (int k = 0; k < 9; ++k) ss += __expf(av[k] - mm);
      alpha = mm + __logf(ss);
    }
    float v = alpha + cend[jj];
    float av[9];
    #pragma unroll
    for (int k = 0; k < 9; ++k) av[k] = __shfl(v, gbase + k);
    float mm = -3e38f;
    #pragma unroll
    for (int k = 0; k < 9; ++k) mm = fmaxf(mm, av[k]);
    float ss = 0.f;
    #pragma unroll
    for (int k = 0; k < 9; ++k) ss += __expf(av[k] - mm);
    if (act && j == 0) denb[b] = mm + __logf(ss);
  }
  __syncthreads();
  if (tid == 0){
    float s = 0.f;
    #pragma unroll
    for (int b = 0; b < 8; ++b) s += numb[b] - denb[b];
    out[0] = -(s * 0.125f);
  }
}

// ---------- host ----------
extern "C" void kernel_launch(void* const* d_in, const int* in_sizes, int n_in,
                              void* d_out, int out_size, void* d_ws, size_t ws_size,
                              hipStream_t stream){
  const int*   input_ids = (const int*)d_in[0];
  const int*   amask     = (const int*)d_in[1];
  const int*   ttids     = (const int*)d_in[2];
  const int*   labels    = (const int*)d_in[3];
  const float* word_emb  = (const float*)d_in[4];
  const float* pos_emb   = (const float*)d_in[5];
  const float* type_emb  = (const float*)d_in[6];
  const float* eln_s     = (const float*)d_in[7];
  const float* eln_b     = (const float*)d_in[8];
  const float* Wqkv      = (const float*)d_in[9];
  const float* bqkv      = (const float*)d_in[10];
  const float* Wo        = (const float*)d_in[11];
  const float* bo        = (const float*)d_in[12];
  const float* ln1s      = (const float*)d_in[13];
  const float* ln1b      = (const float*)d_in[14];
  const float* W1        = (const float*)d_in[15];
  const float* b1        = (const float*)d_in[16];
  const float* W2        = (const float*)d_in[17];
  const float* b2        = (const float*)d_in[18];
  const float* ln2s      = (const float*)d_in[19];
  const float* ln2b      = (const float*)d_in[20];
  const float* Wt        = (const float*)d_in[21];
  const float* bt        = (const float*)d_in[22];
  const float* cstart    = (const float*)d_in[23];
  const float* cend      = (const float*)d_in[24];
  const float* ctrans    = (const float*)d_in[25];

  char* w = (char*)d_ws;
  auto alloc = [&](size_t sz){ char* p = w; w += (sz + 255) & ~(size_t)255; return p; };
  u16*   xb     = (u16*)  alloc(4096ULL * 768 * 2);
  u16*   qkvb   = (u16*)  alloc(4096ULL * 2304 * 2);
  u16*   ctxb   = (u16*)  alloc(4096ULL * 768 * 2);
  u16*   tmpb   = (u16*)  alloc(4096ULL * 768 * 2);
  u16*   hb     = (u16*)  alloc(4096ULL * 3072 * 2);
  u16*   Vtb    = (u16*)  alloc(96ULL * 64 * 512 * 2);
  u16*   Wqkv_b = (u16*)  alloc(2304ULL * 768 * 2);
  u16*   Wo_b   = (u16*)  alloc(768ULL * 768 * 2);
  u16*   W1_b   = (u16*)  alloc(3072ULL * 768 * 2);
  u16*   W2_b   = (u16*)  alloc(768ULL * 3072 * 2);
  float* emis   = (float*)alloc(8ULL * 512 * 9 * 4);
  float* chunkP = (float*)alloc(8ULL * 16 * 81 * 4);
  (void)ws_size; (void)in_sizes; (void)n_in; (void)out_size;

  embed_ln<<<1024, 256, 0, stream>>>(input_ids, ttids, word_emb, pos_emb, type_emb,
                                     eln_s, eln_b, xb);
  for (int l = 0; l < 12; ++l){
    transcvt<<<dim3(72, 24), 256, 0, stream>>>(Wqkv + (size_t)l * 768 * 2304, Wqkv_b, 768, 2304);
    gemm_bt<0><<<dim3(18, 32), 256, 0, stream>>>(xb, Wqkv_b, bqkv + (size_t)l * 2304, qkvb,
                                                 4096, 2304, 768);
    vtrans<<<dim3(16, 2, 96), 256, 0, stream>>>(qkvb, Vtb);
    attn_fused<<<dim3(8, 12, 8), 256, 0, stream>>>(qkvb, amask, Vtb, ctxb);
    transcvt<<<dim3(24, 24), 256, 0, stream>>>(Wo + (size_t)l * 768 * 768, Wo_b, 768, 768);
    gemm_bt<0><<<dim3(6, 32), 256, 0, stream>>>(ctxb, Wo_b, bo + (size_t)l * 768, tmpb,
                                                4096, 768, 768);
    res_ln<<<1024, 256, 0, stream>>>(tmpb, xb, ln1s + (size_t)l * 768, ln1b + (size_t)l * 768, xb);
    transcvt<<<dim3(96, 24), 256, 0, stream>>>(W1 + (size_t)l * 768 * 3072, W1_b, 768, 3072);
    gemm_bt<1><<<dim3(24, 32), 256, 0, stream>>>(xb, W1_b, b1 + (size_t)l * 3072, hb,
                                                 4096, 3072, 768);
    transcvt<<<dim3(24, 96), 256, 0, stream>>>(W2 + (size_t)l * 3072 * 768, W2_b, 3072, 768);
    gemm_bt<0><<<dim3(6, 32), 256, 0, stream>>>(hb, W2_b, b2 + (size_t)l * 768, tmpb,
                                                4096, 768, 3072);
    res_ln<<<1024, 256, 0, stream>>>(tmpb, xb, ln2s + (size_t)l * 768, ln2b + (size_t)l * 768, xb);
  }
  emis_k<<<1024, 256, 0, stream>>>(xb, Wt, bt, emis);
  crf_chunk<<<128, 128, 0, stream>>>(emis, amask, ctrans, chunkP);
  crf_final<<<1, 128, 0, stream>>>(emis, labels, amask, cstart, cend, ctrans, chunkP,
                                   (float*)d_out);
}

// Round 3
// 2253.784 us; speedup vs baseline: 1.1916x; 1.0671x over previous
//
#include <hip/hip_runtime.h>
#include <math.h>

typedef unsigned short u16;
typedef unsigned int u32;
typedef __bf16 bf16x8 __attribute__((ext_vector_type(8)));
typedef float f32x4 __attribute__((ext_vector_type(4)));

// ---------- helpers ----------
__device__ __forceinline__ u16 f2bf(float f){
  unsigned u = __float_as_uint(f);
  unsigned r = u + 0x7fffu + ((u >> 16) & 1u);
  return (u16)(r >> 16);
}
__device__ __forceinline__ float bf2f(u16 h){ return __uint_as_float(((unsigned)h) << 16); }

__device__ __forceinline__ void gload_lds16(const void* g, void* l){
  __builtin_amdgcn_global_load_lds(
      (__attribute__((address_space(1))) void*)(g),
      (__attribute__((address_space(3))) void*)(l), 16, 0, 0);
}
__device__ __forceinline__ f32x4 mfma16(bf16x8 a, bf16x8 b, f32x4 c){
  return __builtin_amdgcn_mfma_f32_16x16x32_bf16(a, b, c, 0, 0, 0);
}
__device__ __forceinline__ float gelu_f(float x){
  float a = 0.7978845608028654f * (x + 0.044715f * x * x * x);
  a = fminf(fmaxf(a, -15.f), 15.f);
  float t = __expf(2.f * a);
  return 0.5f * x * (1.f + (t - 1.f) / (t + 1.f));
}

// ---------- transpose + f32->bf16 convert: W[K][N] -> Wt[N][K] ----------
__global__ __launch_bounds__(256) void transcvt(const float* __restrict__ W,
                                                u16* __restrict__ Wt, int K, int N){
  __shared__ float tile[32][33];
  int tx = threadIdx.x & 31, ty = threadIdx.x >> 5;
  int n0 = blockIdx.x * 32, k0 = blockIdx.y * 32;
  #pragma unroll
  for (int j = 0; j < 32; j += 8)
    tile[ty + j][tx] = W[(size_t)(k0 + ty + j) * N + n0 + tx];
  __syncthreads();
  #pragma unroll
  for (int j = 0; j < 32; j += 8)
    Wt[(size_t)(n0 + ty + j) * K + k0 + tx] = f2bf(tile[tx][ty + j]);
}

// ---------- embedding + layernorm -> bf16 x ----------
__global__ __launch_bounds__(256) void embed_ln(const int* __restrict__ ids,
    const int* __restrict__ tts, const float* __restrict__ we, const float* __restrict__ pe,
    const float* __restrict__ te, const float* __restrict__ g, const float* __restrict__ bb,
    u16* __restrict__ xb){
  int tok = blockIdx.x * 4 + (threadIdx.x >> 6);
  int lane = threadIdx.x & 63;
  int s = tok & 511;
  int id = ids[tok], tt = tts[tok];
  float e[12]; float sum = 0.f, sq = 0.f;
  #pragma unroll
  for (int j = 0; j < 12; ++j){
    int c = lane + j * 64;
    float v = we[(size_t)id * 768 + c] + pe[(size_t)s * 768 + c] + te[(size_t)tt * 768 + c];
    e[j] = v; sum += v; sq += v * v;
  }
  #pragma unroll
  for (int o = 1; o < 64; o <<= 1){ sum += __shfl_xor(sum, o); sq += __shfl_xor(sq, o); }
  float mean = sum * (1.f / 768.f);
  float var = sq * (1.f / 768.f) - mean * mean;
  float inv = rsqrtf(var + 1e-12f);
  size_t base = (size_t)tok * 768;
  #pragma unroll
  for (int j = 0; j < 12; ++j){
    int c = lane + j * 64;
    xb[base + c] = f2bf((e[j] - mean) * inv * g[c] + bb[c]);
  }
}

// ---------- residual add + layernorm (both bf16, vectorized) ----------
__global__ __launch_bounds__(256) void res_ln(const u16* __restrict__ tmp,
    const u16* __restrict__ res, const float* __restrict__ g, const float* __restrict__ bb,
    u16* __restrict__ xout){
  int tok = blockIdx.x * 4 + (threadIdx.x >> 6);
  int lane = threadIdx.x & 63;
  size_t base = (size_t)tok * 768;
  float v[12]; float sum = 0.f, sq = 0.f;
  #pragma unroll
  for (int j = 0; j < 3; ++j){
    int c = j * 256 + lane * 4;
    ushort4 a = *(const ushort4*)(tmp + base + c);
    ushort4 r = *(const ushort4*)(res + base + c);
    const u16* ap = (const u16*)&a; const u16* rp = (const u16*)&r;
    #pragma unroll
    for (int e = 0; e < 4; ++e){
      float f = bf2f(ap[e]) + bf2f(rp[e]);
      v[j * 4 + e] = f; sum += f; sq += f * f;
    }
  }
  #pragma unroll
  for (int o = 1; o < 64; o <<= 1){ sum += __shfl_xor(sum, o); sq += __shfl_xor(sq, o); }
  float mean = sum * (1.f / 768.f);
  float var = sq * (1.f / 768.f) - mean * mean;
  float inv = rsqrtf(var + 1e-12f);
  #pragma unroll
  for (int j = 0; j < 3; ++j){
    int c = j * 256 + lane * 4;
    f32x4 gs = *(const f32x4*)(g + c);
    f32x4 bs = *(const f32x4*)(bb + c);
    ushort4 o; u16* op = (u16*)&o;
    #pragma unroll
    for (int e = 0; e < 4; ++e)
      op[e] = f2bf((v[j * 4 + e] - mean) * inv * gs[e] + bs[e]);
    *(ushort4*)(xout + base + c) = o;
  }
}

// ---------- GEMM: C = A[M][K](bf16) * Bt[N][K]^T (bf16) + bias ----------
// EPI 0: -> bf16 ; 1: gelu -> bf16
// XCD-aware bijective swizzle: grid.x*grid.y must be divisible by 8.
template<int EPI>
__global__ __launch_bounds__(256, 2)
void gemm_bt(const u16* __restrict__ A, const u16* __restrict__ Bt,
             const float* __restrict__ bias, void* __restrict__ Cout,
             int M, int N, int K){
  __shared__ u16 lA[128 * 32];
  __shared__ u16 lB[128 * 32];
  const int tid = threadIdx.x, lane = tid & 63, wv = tid >> 6;
  const int wm = wv >> 1, wn = wv & 1;
  // XCD swizzle: each XCD gets a contiguous chunk of blocks so consecutive
  // blocks sharing an A-panel co-reside in one XCD's L2.
  int gx = gridDim.x;
  int nwg = gx * gridDim.y;
  int bid = blockIdx.y * gx + blockIdx.x;
  int cpx = nwg >> 3;
  int swz = (bid & 7) * cpx + (bid >> 3);
  int bx = swz % gx, by = swz / gx;
  const int row0 = by * 128, col0 = bx * 128;
  f32x4 acc[4][4] = {};
  int aoff[4], boff[4];
  #pragma unroll
  for (int m = 0; m < 4; ++m){
    int r = wm * 64 + m * 16 + (lane & 15);
    int p = (lane >> 4) ^ ((r >> 1) & 3);
    aoff[m] = r * 64 + p * 16;
  }
  #pragma unroll
  for (int n = 0; n < 4; ++n){
    int r = wn * 64 + n * 16 + (lane & 15);
    int p = (lane >> 4) ^ ((r >> 1) & 3);
    boff[n] = r * 64 + p * 16;
  }
  for (int k0 = 0; k0 < K; k0 += 32){
    #pragma unroll
    for (int s = 0; s < 2; ++s){
      int i = s * 256 + tid;
      int r = i >> 2, p = i & 3;
      int sk = k0 + ((p ^ ((r >> 1) & 3)) << 3);
      gload_lds16(A + (size_t)(row0 + r) * K + sk, (char*)lA + i * 16);
      gload_lds16(Bt + (size_t)(col0 + r) * K + sk, (char*)lB + i * 16);
    }
    __syncthreads();
    bf16x8 af[4], bfv[4];
    #pragma unroll
    for (int m = 0; m < 4; ++m) af[m] = *(const bf16x8*)((const char*)lA + aoff[m]);
    #pragma unroll
    for (int n = 0; n < 4; ++n) bfv[n] = *(const bf16x8*)((const char*)lB + boff[n]);
    #pragma unroll
    for (int m = 0; m < 4; ++m)
      #pragma unroll
      for (int n = 0; n < 4; ++n)
        acc[m][n] = mfma16(af[m], bfv[n], acc[m][n]);
    __syncthreads();
  }
  #pragma unroll
  for (int n = 0; n < 4; ++n){
    int gc = col0 + wn * 64 + n * 16 + (lane & 15);
    float bv = bias[gc];
    #pragma unroll
    for (int m = 0; m < 4; ++m){
      int gr = row0 + wm * 64 + m * 16 + (lane >> 4) * 4;
      #pragma unroll
      for (int j = 0; j < 4; ++j){
        float v = acc[m][n][j] + bv;
        if (EPI == 1) v = gelu_f(v);
        ((u16*)Cout)[(size_t)(gr + j) * N + gc] = f2bf(v);
      }
    }
  }
}

// ---------- V transpose: qkv v-section -> Vt[bh][d][k] ----------
__global__ __launch_bounds__(256) void vtrans(const u16* __restrict__ qkv, u16* __restrict__ Vt){
  __shared__ u16 t[32][33];
  int bh = blockIdx.z; int b = bh / 12, h = bh % 12;
  int tx = threadIdx.x & 31, ty = threadIdx.x >> 5;
  int k0 = blockIdx.x * 32, d0 = blockIdx.y * 32;
  const u16* src = qkv + (size_t)b * 512 * 2304 + 1536 + (size_t)h * 64;
  #pragma unroll
  for (int j = 0; j < 32; j += 8)
    t[ty + j][tx] = src[(size_t)(k0 + ty + j) * 2304 + d0 + tx];
  __syncthreads();
  u16* dst = Vt + (size_t)bh * 64 * 512;
  #pragma unroll
  for (int j = 0; j < 32; j += 8)
    dst[(size_t)(d0 + ty + j) * 512 + k0 + tx] = t[tx][ty + j];
}

// ---------- fused attention: S^T = K·Q^T, per-lane softmax, PV ----------
// Block remap: XCD k owns 12 whole heads (K/V L2-resident per XCD).
__global__ __launch_bounds__(256, 2) void attn_fused(const u16* __restrict__ qkv,
    const int* __restrict__ amask, const u16* __restrict__ Vt, u16* __restrict__ ctx){
  __shared__ u16 lQ[64 * 64];
  __shared__ u16 lK[128 * 64];   // scores phase: K chunk; PV phase: per-wave P buffers
  __shared__ u16 lV[64 * 128];
  __shared__ float lbias[512];
  int i = (blockIdx.z * gridDim.y + blockIdx.y) * gridDim.x + blockIdx.x;
  int xcd = i & 7, slot = i >> 3;
  int bh = xcd * 12 + (slot >> 3);
  int q0 = (slot & 7) * 64;
  int b = bh / 12, h = bh % 12;
  int tid = threadIdx.x, lane = tid & 63, wv = tid >> 6;
  int q15 = lane & 15, g = lane >> 4;
  const size_t ld = 2304;
  const u16* base = qkv + (size_t)b * 512 * ld + (size_t)h * 64;
  #pragma unroll
  for (int s = 0; s < 2; ++s){
    int ii = s * 256 + tid, r = ii >> 3, p = ii & 7;
    gload_lds16(base + (size_t)(q0 + r) * ld + ((p ^ (r & 7)) << 3), (char*)lQ + ii * 16);
  }
  for (int ix = tid; ix < 512; ix += 256)
    lbias[ix] = (1.f - (float)amask[(size_t)b * 512 + ix]) * -1e9f;
  f32x4 acc[32];
  #pragma unroll
  for (int ii = 0; ii < 32; ++ii) acc[ii] = {};
  int mr = wv * 16 + q15;
  bf16x8 aq[2];
  #pragma unroll
  for (int c = 0; c < 4; ++c){
    #pragma unroll
    for (int s = 0; s < 4; ++s){
      int ii = s * 256 + tid, r = ii >> 3, p = ii & 7;
      gload_lds16(base + 768 + (size_t)(c * 128 + r) * ld + ((p ^ (r & 7)) << 3),
                  (char*)lK + ii * 16);
    }
    __syncthreads();
    if (c == 0){
      #pragma unroll
      for (int ks = 0; ks < 2; ++ks){
        int slog = ks * 4 + g;
        aq[ks] = *(const bf16x8*)((const char*)lQ + mr * 128 + ((slog ^ (mr & 7)) << 4));
      }
    }
    #pragma unroll
    for (int nf = 0; nf < 8; ++nf){
      int kr = nf * 16 + q15;
      #pragma unroll
      for (int ks = 0; ks < 2; ++ks){
        int slog = ks * 4 + g;
        bf16x8 bk = *(const bf16x8*)((const char*)lK + kr * 128 + ((slog ^ (kr & 7)) << 4));
        acc[c * 8 + nf] = mfma16(bk, aq[ks], acc[c * 8 + nf]);   // C[k][q]
      }
    }
    __syncthreads();
  }
  // per-lane softmax: lane owns q = q0+wv*16+q15, k = i*16 + g*4 + j
  float mx = -3e38f;
  #pragma unroll
  for (int ii = 0; ii < 32; ++ii){
    f32x4 b4 = *(const f32x4*)((const char*)lbias + ii * 64 + g * 16);
    #pragma unroll
    for (int j = 0; j < 4; ++j){
      float v = acc[ii][j] * 0.125f + b4[j];
      acc[ii][j] = v; mx = fmaxf(mx, v);
    }
  }
  mx = fmaxf(mx, __shfl_xor(mx, 16));
  mx = fmaxf(mx, __shfl_xor(mx, 32));
  float sm = 0.f;
  #pragma unroll
  for (int ii = 0; ii < 32; ++ii)
    #pragma unroll
    for (int j = 0; j < 4; ++j){ float p = __expf(acc[ii][j] - mx); acc[ii][j] = p; sm += p; }
  sm += __shfl_xor(sm, 16);
  sm += __shfl_xor(sm, 32);
  float inv = 1.f / sm;
  // PV
  const u16* Vg = Vt + (size_t)(b * 12 + h) * 64 * 512;
  f32x4 accpv[4] = {};
  char* wvP = (char*)lK + wv * 4096;   // per-wave 16q x 128k bf16, XOR-swizzled
  #pragma unroll
  for (int c = 0; c < 4; ++c){
    #pragma unroll
    for (int s = 0; s < 4; ++s){
      int ii = s * 256 + tid, r = ii >> 4, p = ii & 15;
      gload_lds16(Vg + (size_t)r * 512 + c * 128 + ((p ^ (r & 7)) << 3), (char*)lV + ii * 16);
    }
    #pragma unroll
    for (int i2 = 0; i2 < 8; ++i2){
      int ii = c * 8 + i2;
      u32 w0 = (u32)f2bf(acc[ii][0] * inv) | ((u32)f2bf(acc[ii][1] * inv) << 16);
      u32 w1 = (u32)f2bf(acc[ii][2] * inv) | ((u32)f2bf(acc[ii][3] * inv) << 16);
      int slotp = i2 * 2 + (g >> 1);
      char* ad = wvP + q15 * 256 + ((slotp ^ (q15 & 7)) << 4) + ((g & 1) << 3);
      *(uint2*)ad = uint2{w0, w1};
    }
    __syncthreads();
    #pragma unroll
    for (int s = 0; s < 4; ++s){
      bf16x8 pa = *(const bf16x8*)(wvP + q15 * 256 + (((s * 4 + g) ^ (q15 & 7)) << 4));
      #pragma unroll
      for (int nf = 0; nf < 4; ++nf){
        int dr = nf * 16 + q15;
        bf16x8 bv = *(const bf16x8*)((const char*)lV + dr * 256 + (((s * 4 + g) ^ (dr & 7)) << 4));
        accpv[nf] = mfma16(pa, bv, accpv[nf]);
      }
    }
    __syncthreads();
  }
  u16* C = ctx + (size_t)b * 512 * 768 + (size_t)h * 64;
  #pragma unroll
  for (int nf = 0; nf < 4; ++nf)
    #pragma unroll
    for (int j = 0; j < 4; ++j){
      int q = q0 + wv * 16 + g * 4 + j;
      int d = nf * 16 + q15;
      C[(size_t)q * 768 + d] = f2bf(accpv[nf][j]);
    }
}

// ---------- emissions: x @ Wt(768x9 f32) + bt -> f32 ----------
__global__ __launch_bounds__(256) void emis_k(const u16* __restrict__ xb,
    const float* __restrict__ Wt, const float* __restrict__ bt, float* __restrict__ emis){
  int row = blockIdx.x * 4 + (threadIdx.x >> 6);
  int lane = threadIdx.x & 63;
  float a[9] = {};
  #pragma unroll
  for (int j = 0; j < 12; ++j){
    int k = lane + j * 64;
    float xv = bf2f(xb[(size_t)row * 768 + k]);
    #pragma unroll
    for (int t = 0; t < 9; ++t) a[t] += xv * Wt[(size_t)k * 9 + t];
  }
  #pragma unroll
  for (int o = 1; o < 64; o <<= 1)
    #pragma unroll
    for (int t = 0; t < 9; ++t) a[t] += __shfl_xor(a[t], o);
  if (lane == 0){
    #pragma unroll
    for (int t = 0; t < 9; ++t) emis[(size_t)row * 9 + t] = a[t] + bt[t];
  }
}

// ---------- CRF chunk products: log-semiring 9x9 matrix scan ----------
__global__ __launch_bounds__(128) void crf_chunk(const float* __restrict__ emis,
    const int* __restrict__ amask, const float* __restrict__ ctrans,
    float* __restrict__ chunkP){
  __shared__ float cur[2][96];
  int blk = blockIdx.x; int b = blk >> 4, c = blk & 15;
  int t0 = threadIdx.x;
  bool act = t0 < 81;
  int tc = act ? t0 : 0;
  int i = tc / 9, j = tc - i * 9;
  float tr[9];
  #pragma unroll
  for (int k = 0; k < 9; ++k) tr[k] = ctrans[k * 9 + j];
  const float* eb = emis + (size_t)b * 512 * 9;
  const int* mb = amask + (size_t)b * 512;
  int lo = c * 32 + (c == 0 ? 1 : 0), hi = c * 32 + 31;
  if (act){
    int m = mb[lo];
    cur[0][t0] = m ? (ctrans[i * 9 + j] + eb[(size_t)lo * 9 + j])
                   : (i == j ? 0.f : -1e30f);
  }
  __syncthreads();
  int pp = 0;
  for (int t = lo + 1; t <= hi; ++t){
    float a[9];
    #pragma unroll
    for (int k = 0; k < 9; ++k) a[k] = cur[pp][i * 9 + k];
    int m = mb[t];
    float outv;
    if (m){
      float ej = eb[(size_t)t * 9 + j];
      float mm = -3e38f;
      #pragma unroll
      for (int k = 0; k < 9; ++k){ a[k] += tr[k]; mm = fmaxf(mm, a[k]); }
      float ss = 0.f;
      #pragma unroll
      for (int k = 0; k < 9; ++k) ss += __expf(a[k] - mm);
      outv = ej + mm + __logf(ss);
    } else {
      outv = a[j];
    }
    if (act) cur[pp ^ 1][t0] = outv;
    __syncthreads();
    pp ^= 1;
  }
  if (act) chunkP[(size_t)(b * 16 + c) * 81 + t0] = cur[pp][t0];
}

// ---------- CRF final: numerator + apply chunk products + combine ----------
__global__ __launch_bounds__(128) void crf_final(const float* __restrict__ emis,
    const int* __restrict__ labels, const int* __restrict__ amask,
    const float* __restrict__ cstart, const float* __restrict__ cend,
    const float* __restrict__ ctrans, const float* __restrict__ chunkP,
    float* __restrict__ out){
  __shared__ float numb[8], denb[8];
  int tid = threadIdx.x;
  { // numerator
    int b = tid >> 4, gg = tid & 15;
    const int* lab = labels + (size_t)b * 512;
    const int* msk = amask + (size_t)b * 512;
    float part = 0.f; int cnt = 0;
    for (int i = gg; i < 512; i += 16){
      int m = msk[i]; cnt += m;
      if (i >= 1){
        int tp = lab[i - 1], tcc = lab[i];
        part += (ctrans[tp * 9 + tcc] + emis[((size_t)b * 512 + i) * 9 + tcc]) * (float)m;
      }
    }
    #pragma unroll
    for (int o = 1; o < 16; o <<= 1){ part += __shfl_xor(part, o); cnt += __shfl_xor(cnt, o); }
    if (gg == 0){
      int tt0 = lab[0];
      numb[b] = part + cstart[tt0] + emis[((size_t)b * 512) * 9 + tt0] + cend[lab[cnt - 1]];
    }
  }
  __syncthreads();
  { // denominator via 16 chunk products
    int lane = tid & 63, w = tid >> 6;
    int sub = lane >> 4, j = lane & 15;
    int b = w * 4 + sub;
    bool act = j < 9;
    int jj = act ? j : 0;
    int gbase = lane & 48;
    float alpha = cstart[jj] + emis[(size_t)b * 512 * 9 + jj];
    for (int c = 0; c < 16; ++c){
      const float* P = chunkP + (size_t)(b * 16 + c) * 81;
      float av[9];
      #pragma unroll
      for (int k = 0; k < 9; ++k) av[k] = __shfl(alpha, gbase + k) + P[k * 9 + jj];
      float mm = -3e38f;
      #pragma unroll
      for (int k = 0; k < 9; ++k) mm = fmaxf(mm, av[k]);
      float ss = 0.f;
      #pragma unroll
      for (int k = 0; k < 9; ++k) ss += __expf(av[k] - mm);
      alpha = mm + __logf(ss);
    }
    float v = alpha + cend[jj];
    float av[9];
    #pragma unroll
    for (int k = 0; k < 9; ++k) av[k] = __shfl(v, gbase + k);
    float mm = -3e38f;
    #pragma unroll
    for (int k = 0; k < 9; ++k) mm = fmaxf(mm, av[k]);
    float ss = 0.f;
    #pragma unroll
    for (int k = 0; k < 9; ++k) ss += __expf(av[k] - mm);
    if (act && j == 0) denb[b] = mm + __logf(ss);
  }
  __syncthreads();
  if (tid == 0){
    float s = 0.f;
    #pragma unroll
    for (int b = 0; b < 8; ++b) s += numb[b] - denb[b];
    out[0] = -(s * 0.125f);
  }
}

// ---------- host ----------
extern "C" void kernel_launch(void* const* d_in, const int* in_sizes, int n_in,
                              void* d_out, int out_size, void* d_ws, size_t ws_size,
                              hipStream_t stream){
  const int*   input_ids = (const int*)d_in[0];
  const int*   amask     = (const int*)d_in[1];
  const int*   ttids     = (const int*)d_in[2];
  const int*   labels    = (const int*)d_in[3];
  const float* word_emb  = (const float*)d_in[4];
  const float* pos_emb   = (const float*)d_in[5];
  const float* type_emb  = (const float*)d_in[6];
  const float* eln_s     = (const float*)d_in[7];
  const float* eln_b     = (const float*)d_in[8];
  const float* Wqkv      = (const float*)d_in[9];
  const float* bqkv      = (const float*)d_in[10];
  const float* Wo        = (const float*)d_in[11];
  const float* bo        = (const float*)d_in[12];
  const float* ln1s      = (const float*)d_in[13];
  const float* ln1b      = (const float*)d_in[14];
  const float* W1        = (const float*)d_in[15];
  const float* b1        = (const float*)d_in[16];
  const float* W2        = (const float*)d_in[17];
  const float* b2        = (const float*)d_in[18];
  const float* ln2s      = (const float*)d_in[19];
  const float* ln2b      = (const float*)d_in[20];
  const float* Wt        = (const float*)d_in[21];
  const float* bt        = (const float*)d_in[22];
  const float* cstart    = (const float*)d_in[23];
  const float* cend      = (const float*)d_in[24];
  const float* ctrans    = (const float*)d_in[25];

  char* w = (char*)d_ws;
  auto alloc = [&](size_t sz){ char* p = w; w += (sz + 255) & ~(size_t)255; return p; };
  u16*   xb     = (u16*)  alloc(4096ULL * 768 * 2);
  u16*   qkvb   = (u16*)  alloc(4096ULL * 2304 * 2);
  u16*   ctxb   = (u16*)  alloc(4096ULL * 768 * 2);
  u16*   tmpb   = (u16*)  alloc(4096ULL * 768 * 2);
  u16*   hb     = (u16*)  alloc(4096ULL * 3072 * 2);
  u16*   Vtb    = (u16*)  alloc(96ULL * 64 * 512 * 2);
  u16*   Wqkv_b = (u16*)  alloc(2304ULL * 768 * 2);
  u16*   Wo_b   = (u16*)  alloc(768ULL * 768 * 2);
  u16*   W1_b   = (u16*)  alloc(3072ULL * 768 * 2);
  u16*   W2_b   = (u16*)  alloc(768ULL * 3072 * 2);
  float* emis   = (float*)alloc(8ULL * 512 * 9 * 4);
  float* chunkP = (float*)alloc(8ULL * 16 * 81 * 4);
  (void)ws_size; (void)in_sizes; (void)n_in; (void)out_size;

  embed_ln<<<1024, 256, 0, stream>>>(input_ids, ttids, word_emb, pos_emb, type_emb,
                                     eln_s, eln_b, xb);
  for (int l = 0; l < 12; ++l){
    transcvt<<<dim3(72, 24), 256, 0, stream>>>(Wqkv + (size_t)l * 768 * 2304, Wqkv_b, 768, 2304);
    gemm_bt<0><<<dim3(18, 32), 256, 0, stream>>>(xb, Wqkv_b, bqkv + (size_t)l * 2304, qkvb,
                                                 4096, 2304, 768);
    vtrans<<<dim3(16, 2, 96), 256, 0, stream>>>(qkvb, Vtb);
    attn_fused<<<dim3(8, 12, 8), 256, 0, stream>>>(qkvb, amask, Vtb, ctxb);
    transcvt<<<dim3(24, 24), 256, 0, stream>>>(Wo + (size_t)l * 768 * 768, Wo_b, 768, 768);
    gemm_bt<0><<<dim3(6, 32), 256, 0, stream>>>(ctxb, Wo_b, bo + (size_t)l * 768, tmpb,
                                                4096, 768, 768);
    res_ln<<<1024, 256, 0, stream>>>(tmpb, xb, ln1s + (size_t)l * 768, ln1b + (size_t)l * 768, xb);
    transcvt<<<dim3(96, 24), 256, 0, stream>>>(W1 + (size_t)l * 768 * 3072, W1_b, 768, 3072);
    gemm_bt<1><<<dim3(24, 32), 256, 0, stream>>>(xb, W1_b, b1 + (size_t)l * 3072, hb,
                                                 4096, 3072, 768);
    transcvt<<<dim3(24, 96), 256, 0, stream>>>(W2 + (size_t)l * 3072 * 768, W2_b, 3072, 768);
    gemm_bt<0><<<dim3(6, 32), 256, 0, stream>>>(hb, W2_b, b2 + (size_t)l * 768, tmpb,
                                                4096, 768, 3072);
    res_ln<<<1024, 256, 0, stream>>>(tmpb, xb, ln2s + (size_t)l * 768, ln2b + (size_t)l * 768, xb);
  }
  emis_k<<<1024, 256, 0, stream>>>(xb, Wt, bt, emis);
  crf_chunk<<<128, 128, 0, stream>>>(emis, amask, ctrans, chunkP);
  crf_final<<<1, 128, 0, stream>>>(emis, labels, amask, cstart, cend, ctrans, chunkP,
                                   (float*)d_out);
}

// Round 4
// 2027.192 us; speedup vs baseline: 1.3248x; 1.1118x over previous
//
#include <hip/hip_runtime.h>
#include <math.h>

typedef unsigned short u16;
typedef unsigned int u32;
typedef __bf16 bf16x8 __attribute__((ext_vector_type(8)));
typedef float f32x4 __attribute__((ext_vector_type(4)));

// ---------- helpers ----------
__device__ __forceinline__ u16 f2bf(float f){
  unsigned u = __float_as_uint(f);
  unsigned r = u + 0x7fffu + ((u >> 16) & 1u);
  return (u16)(r >> 16);
}
__device__ __forceinline__ float bf2f(u16 h){ return __uint_as_float(((unsigned)h) << 16); }

__device__ __forceinline__ void gload_lds16(const void* g, void* l){
  __builtin_amdgcn_global_load_lds(
      (__attribute__((address_space(1))) void*)(g),
      (__attribute__((address_space(3))) void*)(l), 16, 0, 0);
}
__device__ __forceinline__ f32x4 mfma16(bf16x8 a, bf16x8 b, f32x4 c){
  return __builtin_amdgcn_mfma_f32_16x16x32_bf16(a, b, c, 0, 0, 0);
}
__device__ __forceinline__ float gelu_f(float x){
  float a = 0.7978845608028654f * (x + 0.044715f * x * x * x);
  a = fminf(fmaxf(a, -15.f), 15.f);
  float t = __expf(2.f * a);
  return 0.5f * x * (1.f + (t - 1.f) / (t + 1.f));
}

// ---------- transpose + f32->bf16 convert: W[l][K][N] -> Wt[l][N][K] ----------
__global__ __launch_bounds__(256) void transcvt_l(const float* __restrict__ W,
                                                  u16* __restrict__ Wt, int K, int N){
  int l = blockIdx.z;
  W  += (size_t)l * K * N;
  Wt += (size_t)l * N * K;
  __shared__ float tile[32][33];
  int tx = threadIdx.x & 31, ty = threadIdx.x >> 5;
  int n0 = blockIdx.x * 32, k0 = blockIdx.y * 32;
  #pragma unroll
  for (int j = 0; j < 32; j += 8)
    tile[ty + j][tx] = W[(size_t)(k0 + ty + j) * N + n0 + tx];
  __syncthreads();
  #pragma unroll
  for (int j = 0; j < 32; j += 8)
    Wt[(size_t)(n0 + ty + j) * K + k0 + tx] = f2bf(tile[tx][ty + j]);
}

// ---------- embedding + layernorm -> bf16 x ----------
__global__ __launch_bounds__(256) void embed_ln(const int* __restrict__ ids,
    const int* __restrict__ tts, const float* __restrict__ we, const float* __restrict__ pe,
    const float* __restrict__ te, const float* __restrict__ g, const float* __restrict__ bb,
    u16* __restrict__ xb){
  int tok = blockIdx.x * 4 + (threadIdx.x >> 6);
  int lane = threadIdx.x & 63;
  int s = tok & 511;
  int id = ids[tok], tt = tts[tok];
  float e[12]; float sum = 0.f, sq = 0.f;
  #pragma unroll
  for (int j = 0; j < 12; ++j){
    int c = lane + j * 64;
    float v = we[(size_t)id * 768 + c] + pe[(size_t)s * 768 + c] + te[(size_t)tt * 768 + c];
    e[j] = v; sum += v; sq += v * v;
  }
  #pragma unroll
  for (int o = 1; o < 64; o <<= 1){ sum += __shfl_xor(sum, o); sq += __shfl_xor(sq, o); }
  float mean = sum * (1.f / 768.f);
  float var = sq * (1.f / 768.f) - mean * mean;
  float inv = rsqrtf(var + 1e-12f);
  size_t base = (size_t)tok * 768;
  #pragma unroll
  for (int j = 0; j < 12; ++j){
    int c = lane + j * 64;
    xb[base + c] = f2bf((e[j] - mean) * inv * g[c] + bb[c]);
  }
}

// ---------- residual add + layernorm (both bf16, vectorized) ----------
__global__ __launch_bounds__(256) void res_ln(const u16* __restrict__ tmp,
    const u16* __restrict__ res, const float* __restrict__ g, const float* __restrict__ bb,
    u16* __restrict__ xout){
  int tok = blockIdx.x * 4 + (threadIdx.x >> 6);
  int lane = threadIdx.x & 63;
  size_t base = (size_t)tok * 768;
  float v[12]; float sum = 0.f, sq = 0.f;
  #pragma unroll
  for (int j = 0; j < 3; ++j){
    int c = j * 256 + lane * 4;
    ushort4 a = *(const ushort4*)(tmp + base + c);
    ushort4 r = *(const ushort4*)(res + base + c);
    const u16* ap = (const u16*)&a; const u16* rp = (const u16*)&r;
    #pragma unroll
    for (int e = 0; e < 4; ++e){
      float f = bf2f(ap[e]) + bf2f(rp[e]);
      v[j * 4 + e] = f; sum += f; sq += f * f;
    }
  }
  #pragma unroll
  for (int o = 1; o < 64; o <<= 1){ sum += __shfl_xor(sum, o); sq += __shfl_xor(sq, o); }
  float mean = sum * (1.f / 768.f);
  float var = sq * (1.f / 768.f) - mean * mean;
  float inv = rsqrtf(var + 1e-12f);
  #pragma unroll
  for (int j = 0; j < 3; ++j){
    int c = j * 256 + lane * 4;
    f32x4 gs = *(const f32x4*)(g + c);
    f32x4 bs = *(const f32x4*)(bb + c);
    ushort4 o; u16* op = (u16*)&o;
    #pragma unroll
    for (int e = 0; e < 4; ++e)
      op[e] = f2bf((v[j * 4 + e] - mean) * inv * gs[e] + bs[e]);
    *(ushort4*)(xout + base + c) = o;
  }
}

// ---------- GEMM: C = A[M][K](bf16) * Bt[N][K]^T (bf16) + bias ----------
// BK=64, 2 barriers per 64-K. EPI 0: -> bf16 ; 1: gelu -> bf16
// XSPLIT=2: XCDs arranged 2(bx) x 4(by); XSPLIT=1: XCDs own by-rows (A read once).
template<int EPI, int XSPLIT>
__global__ __launch_bounds__(256, 2)
void gemm_bt(const u16* __restrict__ A, const u16* __restrict__ Bt,
             const float* __restrict__ bias, void* __restrict__ Cout,
             int M, int N, int K){
  __shared__ u16 lA[128 * 64];
  __shared__ u16 lB[128 * 64];
  const int tid = threadIdx.x, lane = tid & 63, wv = tid >> 6;
  const int wm = wv >> 1, wn = wv & 1;
  const int gx = gridDim.x, gy = gridDim.y;
  int bid = blockIdx.y * gx + blockIdx.x;
  int xcd = bid & 7, idx = bid >> 3;
  int bx, by;
  if (XSPLIT == 2){
    int cw = gx >> 1, ch = gy >> 2;
    bx = (xcd >> 2) * cw + idx % cw;
    by = (xcd & 3) * ch + idx / cw;
  } else {
    int ch = gy >> 3;
    bx = idx % gx;
    by = xcd * ch + idx / gx;
  }
  const int row0 = by * 128, col0 = bx * 128;
  f32x4 acc[4][4] = {};
  for (int k0 = 0; k0 < K; k0 += 64){
    #pragma unroll
    for (int s = 0; s < 4; ++s){
      int i = s * 256 + tid;
      int r = i >> 3, p = i & 7;
      int sk = k0 + ((p ^ (r & 7)) << 3);   // pre-swizzled global source
      gload_lds16(A + (size_t)(row0 + r) * K + sk, (char*)lA + i * 16);
      gload_lds16(Bt + (size_t)(col0 + r) * K + sk, (char*)lB + i * 16);
    }
    __syncthreads();
    int g = lane >> 4;
    #pragma unroll
    for (int kk = 0; kk < 2; ++kk){
      bf16x8 af[4], bfv[4];
      #pragma unroll
      for (int m = 0; m < 4; ++m){
        int r = wm * 64 + m * 16 + (lane & 15);
        af[m] = *(const bf16x8*)((const char*)lA + r * 128 + (((kk * 4 + g) ^ (r & 7)) << 4));
      }
      #pragma unroll
      for (int n = 0; n < 4; ++n){
        int r = wn * 64 + n * 16 + (lane & 15);
        bfv[n] = *(const bf16x8*)((const char*)lB + r * 128 + (((kk * 4 + g) ^ (r & 7)) << 4));
      }
      #pragma unroll
      for (int m = 0; m < 4; ++m)
        #pragma unroll
        for (int n = 0; n < 4; ++n)
          acc[m][n] = mfma16(af[m], bfv[n], acc[m][n]);
    }
    __syncthreads();
  }
  #pragma unroll
  for (int n = 0; n < 4; ++n){
    int gc = col0 + wn * 64 + n * 16 + (lane & 15);
    float bv = bias[gc];
    #pragma unroll
    for (int m = 0; m < 4; ++m){
      int gr = row0 + wm * 64 + m * 16 + (lane >> 4) * 4;
      #pragma unroll
      for (int j = 0; j < 4; ++j){
        float v = acc[m][n][j] + bv;
        if (EPI == 1) v = gelu_f(v);
        ((u16*)Cout)[(size_t)(gr + j) * N + gc] = f2bf(v);
      }
    }
  }
}

// ---------- V transpose: qkv v-section -> Vt[bh][d][k] ----------
__global__ __launch_bounds__(256) void vtrans(const u16* __restrict__ qkv, u16* __restrict__ Vt){
  __shared__ u16 t[32][33];
  int bh = blockIdx.z; int b = bh / 12, h = bh % 12;
  int tx = threadIdx.x & 31, ty = threadIdx.x >> 5;
  int k0 = blockIdx.x * 32, d0 = blockIdx.y * 32;
  const u16* src = qkv + (size_t)b * 512 * 2304 + 1536 + (size_t)h * 64;
  #pragma unroll
  for (int j = 0; j < 32; j += 8)
    t[ty + j][tx] = src[(size_t)(k0 + ty + j) * 2304 + d0 + tx];
  __syncthreads();
  u16* dst = Vt + (size_t)bh * 64 * 512;
  #pragma unroll
  for (int j = 0; j < 32; j += 8)
    dst[(size_t)(d0 + ty + j) * 512 + k0 + tx] = t[tx][ty + j];
}

// ---------- fused attention: S^T = K·Q^T, per-lane softmax, PV ----------
// XCD k owns 12 whole heads (K/V L2-resident per XCD).
__global__ __launch_bounds__(256, 2) void attn_fused(const u16* __restrict__ qkv,
    const int* __restrict__ amask, const u16* __restrict__ Vt, u16* __restrict__ ctx){
  __shared__ u16 lQ[64 * 64];
  __shared__ u16 lK[128 * 64];   // scores phase: K chunk; PV phase: per-wave P buffers
  __shared__ u16 lV[64 * 128];
  __shared__ float lbias[512];
  int i = (blockIdx.z * gridDim.y + blockIdx.y) * gridDim.x + blockIdx.x;
  int xcd = i & 7, slot = i >> 3;
  int bh = xcd * 12 + (slot >> 3);
  int q0 = (slot & 7) * 64;
  int b = bh / 12, h = bh % 12;
  int tid = threadIdx.x, lane = tid & 63, wv = tid >> 6;
  int q15 = lane & 15, g = lane >> 4;
  const size_t ld = 2304;
  const u16* base = qkv + (size_t)b * 512 * ld + (size_t)h * 64;
  #pragma unroll
  for (int s = 0; s < 2; ++s){
    int ii = s * 256 + tid, r = ii >> 3, p = ii & 7;
    gload_lds16(base + (size_t)(q0 + r) * ld + ((p ^ (r & 7)) << 3), (char*)lQ + ii * 16);
  }
  for (int ix = tid; ix < 512; ix += 256)
    lbias[ix] = (1.f - (float)amask[(size_t)b * 512 + ix]) * -1e9f;
  f32x4 acc[32];
  #pragma unroll
  for (int ii = 0; ii < 32; ++ii) acc[ii] = {};
  int mr = wv * 16 + q15;
  bf16x8 aq[2];
  #pragma unroll
  for (int c = 0; c < 4; ++c){
    #pragma unroll
    for (int s = 0; s < 4; ++s){
      int ii = s * 256 + tid, r = ii >> 3, p = ii & 7;
      gload_lds16(base + 768 + (size_t)(c * 128 + r) * ld + ((p ^ (r & 7)) << 3),
                  (char*)lK + ii * 16);
    }
    __syncthreads();
    if (c == 0){
      #pragma unroll
      for (int ks = 0; ks < 2; ++ks){
        int slog = ks * 4 + g;
        aq[ks] = *(const bf16x8*)((const char*)lQ + mr * 128 + ((slog ^ (mr & 7)) << 4));
      }
    }
    #pragma unroll
    for (int nf = 0; nf < 8; ++nf){
      int kr = nf * 16 + q15;
      #pragma unroll
      for (int ks = 0; ks < 2; ++ks){
        int slog = ks * 4 + g;
        bf16x8 bk = *(const bf16x8*)((const char*)lK + kr * 128 + ((slog ^ (kr & 7)) << 4));
        acc[c * 8 + nf] = mfma16(bk, aq[ks], acc[c * 8 + nf]);   // C[k][q]
      }
    }
    __syncthreads();
  }
  // per-lane softmax: lane owns q = q0+wv*16+q15, k = i*16 + g*4 + j
  float mx = -3e38f;
  #pragma unroll
  for (int ii = 0; ii < 32; ++ii){
    f32x4 b4 = *(const f32x4*)((const char*)lbias + ii * 64 + g * 16);
    #pragma unroll
    for (int j = 0; j < 4; ++j){
      float v = acc[ii][j] * 0.125f + b4[j];
      acc[ii][j] = v; mx = fmaxf(mx, v);
    }
  }
  mx = fmaxf(mx, __shfl_xor(mx, 16));
  mx = fmaxf(mx, __shfl_xor(mx, 32));
  float sm = 0.f;
  #pragma unroll
  for (int ii = 0; ii < 32; ++ii)
    #pragma unroll
    for (int j = 0; j < 4; ++j){ float p = __expf(acc[ii][j] - mx); acc[ii][j] = p; sm += p; }
  sm += __shfl_xor(sm, 16);
  sm += __shfl_xor(sm, 32);
  float inv = 1.f / sm;
  // PV
  const u16* Vg = Vt + (size_t)(b * 12 + h) * 64 * 512;
  f32x4 accpv[4] = {};
  char* wvP = (char*)lK + wv * 4096;   // per-wave 16q x 128k bf16, XOR-swizzled
  #pragma unroll
  for (int c = 0; c < 4; ++c){
    #pragma unroll
    for (int s = 0; s < 4; ++s){
      int ii = s * 256 + tid, r = ii >> 4, p = ii & 15;
      gload_lds16(Vg + (size_t)r * 512 + c * 128 + ((p ^ (r & 7)) << 3), (char*)lV + ii * 16);
    }
    #pragma unroll
    for (int i2 = 0; i2 < 8; ++i2){
      int ii = c * 8 + i2;
      u32 w0 = (u32)f2bf(acc[ii][0] * inv) | ((u32)f2bf(acc[ii][1] * inv) << 16);
      u32 w1 = (u32)f2bf(acc[ii][2] * inv) | ((u32)f2bf(acc[ii][3] * inv) << 16);
      int slotp = i2 * 2 + (g >> 1);
      char* ad = wvP + q15 * 256 + ((slotp ^ (q15 & 7)) << 4) + ((g & 1) << 3);
      *(uint2*)ad = uint2{w0, w1};
    }
    __syncthreads();
    #pragma unroll
    for (int s = 0; s < 4; ++s){
      bf16x8 pa = *(const bf16x8*)(wvP + q15 * 256 + (((s * 4 + g) ^ (q15 & 7)) << 4));
      #pragma unroll
      for (int nf = 0; nf < 4; ++nf){
        int dr = nf * 16 + q15;
        bf16x8 bv = *(const bf16x8*)((const char*)lV + dr * 256 + (((s * 4 + g) ^ (dr & 7)) << 4));
        accpv[nf] = mfma16(pa, bv, accpv[nf]);
      }
    }
    __syncthreads();
  }
  u16* C = ctx + (size_t)b * 512 * 768 + (size_t)h * 64;
  #pragma unroll
  for (int nf = 0; nf < 4; ++nf)
    #pragma unroll
    for (int j = 0; j < 4; ++j){
      int q = q0 + wv * 16 + g * 4 + j;
      int d = nf * 16 + q15;
      C[(size_t)q * 768 + d] = f2bf(accpv[nf][j]);
    }
}

// ---------- emissions: x @ Wt(768x9 f32) + bt -> f32 ----------
__global__ __launch_bounds__(256) void emis_k(const u16* __restrict__ xb,
    const float* __restrict__ Wt, const float* __restrict__ bt, float* __restrict__ emis){
  int row = blockIdx.x * 4 + (threadIdx.x >> 6);
  int lane = threadIdx.x & 63;
  float a[9] = {};
  #pragma unroll
  for (int j = 0; j < 12; ++j){
    int k = lane + j * 64;
    float xv = bf2f(xb[(size_t)row * 768 + k]);
    #pragma unroll
    for (int t = 0; t < 9; ++t) a[t] += xv * Wt[(size_t)k * 9 + t];
  }
  #pragma unroll
  for (int o = 1; o < 64; o <<= 1)
    #pragma unroll
    for (int t = 0; t < 9; ++t) a[t] += __shfl_xor(a[t], o);
  if (lane == 0){
    #pragma unroll
    for (int t = 0; t < 9; ++t) emis[(size_t)row * 9 + t] = a[t] + bt[t];
  }
}

// ---------- CRF chunk products: log-semiring 9x9 matrix scan ----------
__global__ __launch_bounds__(128) void crf_chunk(const float* __restrict__ emis,
    const int* __restrict__ amask, const float* __restrict__ ctrans,
    float* __restrict__ chunkP){
  __shared__ float cur[2][96];
  int blk = blockIdx.x; int b = blk >> 4, c = blk & 15;
  int t0 = threadIdx.x;
  bool act = t0 < 81;
  int tc = act ? t0 : 0;
  int i = tc / 9, j = tc - i * 9;
  float tr[9];
  #pragma unroll
  for (int k = 0; k < 9; ++k) tr[k] = ctrans[k * 9 + j];
  const float* eb = emis + (size_t)b * 512 * 9;
  const int* mb = amask + (size_t)b * 512;
  int lo = c * 32 + (c == 0 ? 1 : 0), hi = c * 32 + 31;
  if (act){
    int m = mb[lo];
    cur[0][t0] = m ? (ctrans[i * 9 + j] + eb[(size_t)lo * 9 + j])
                   : (i == j ? 0.f : -1e30f);
  }
  __syncthreads();
  int pp = 0;
  for (int t = lo + 1; t <= hi; ++t){
    float a[9];
    #pragma unroll
    for (int k = 0; k < 9; ++k) a[k] = cur[pp][i * 9 + k];
    int m = mb[t];
    float outv;
    if (m){
      float ej = eb[(size_t)t * 9 + j];
      float mm = -3e38f;
      #pragma unroll
      for (int k = 0; k < 9; ++k){ a[k] += tr[k]; mm = fmaxf(mm, a[k]); }
      float ss = 0.f;
      #pragma unroll
      for (int k = 0; k < 9; ++k) ss += __expf(a[k] - mm);
      outv = ej + mm + __logf(ss);
    } else {
      outv = a[j];
    }
    if (act) cur[pp ^ 1][t0] = outv;
    __syncthreads();
    pp ^= 1;
  }
  if (act) chunkP[(size_t)(b * 16 + c) * 81 + t0] = cur[pp][t0];
}

// ---------- CRF final: numerator + apply chunk products + combine ----------
__global__ __launch_bounds__(128) void crf_final(const float* __restrict__ emis,
    const int* __restrict__ labels, const int* __restrict__ amask,
    const float* __restrict__ cstart, const float* __restrict__ cend,
    const float* __restrict__ ctrans, const float* __restrict__ chunkP,
    float* __restrict__ out){
  __shared__ float numb[8], denb[8];
  int tid = threadIdx.x;
  { // numerator
    int b = tid >> 4, gg = tid & 15;
    const int* lab = labels + (size_t)b * 512;
    const int* msk = amask + (size_t)b * 512;
    float part = 0.f; int cnt = 0;
    for (int i = gg; i < 512; i += 16){
      int m = msk[i]; cnt += m;
      if (i >= 1){
        int tp = lab[i - 1], tcc = lab[i];
        part += (ctrans[tp * 9 + tcc] + emis[((size_t)b * 512 + i) * 9 + tcc]) * (float)m;
      }
    }
    #pragma unroll
    for (int o = 1; o < 16; o <<= 1){ part += __shfl_xor(part, o); cnt += __shfl_xor(cnt, o); }
    if (gg == 0){
      int tt0 = lab[0];
      numb[b] = part + cstart[tt0] + emis[((size_t)b * 512) * 9 + tt0] + cend[lab[cnt - 1]];
    }
  }
  __syncthreads();
  { // denominator via 16 chunk products
    int lane = tid & 63, w = tid >> 6;
    int sub = lane >> 4, j = lane & 15;
    int b = w * 4 + sub;
    bool act = j < 9;
    int jj = act ? j : 0;
    int gbase = lane & 48;
    float alpha = cstart[jj] + emis[(size_t)b * 512 * 9 + jj];
    for (int c = 0; c < 16; ++c){
      const float* P = chunkP + (size_t)(b * 16 + c) * 81;
      float av[9];
      #pragma unroll
      for (int k = 0; k < 9; ++k) av[k] = __shfl(alpha, gbase + k) + P[k * 9 + jj];
      float mm = -3e38f;
      #pragma unroll
      for (int k = 0; k < 9; ++k) mm = fmaxf(mm, av[k]);
      float ss = 0.f;
      #pragma unroll
      for (int k = 0; k < 9; ++k) ss += __expf(av[k] - mm);
      alpha = mm + __logf(ss);
    }
    float v = alpha + cend[jj];
    float av[9];
    #pragma unroll
    for (int k = 0; k < 9; ++k) av[k] = __shfl(v, gbase + k);
    float mm = -3e38f;
    #pragma unroll
    for (int k = 0; k < 9; ++k) mm = fmaxf(mm, av[k]);
    float ss = 0.f;
    #pragma unroll
    for (int k = 0; k < 9; ++k) ss += __expf(av[k] - mm);
    if (act && j == 0) denb[b] = mm + __logf(ss);
  }
  __syncthreads();
  if (tid == 0){
    float s = 0.f;
    #pragma unroll
    for (int b = 0; b < 8; ++b) s += numb[b] - denb[b];
    out[0] = -(s * 0.125f);
  }
}

// ---------- host ----------
extern "C" void kernel_launch(void* const* d_in, const int* in_sizes, int n_in,
                              void* d_out, int out_size, void* d_ws, size_t ws_size,
                              hipStream_t stream){
  const int*   input_ids = (const int*)d_in[0];
  const int*   amask     = (const int*)d_in[1];
  const int*   ttids     = (const int*)d_in[2];
  const int*   labels    = (const int*)d_in[3];
  const float* word_emb  = (const float*)d_in[4];
  const float* pos_emb   = (const float*)d_in[5];
  const float* type_emb  = (const float*)d_in[6];
  const float* eln_s     = (const float*)d_in[7];
  const float* eln_b     = (const float*)d_in[8];
  const float* Wqkv      = (const float*)d_in[9];
  const float* bqkv      = (const float*)d_in[10];
  const float* Wo        = (const float*)d_in[11];
  const float* bo        = (const float*)d_in[12];
  const float* ln1s      = (const float*)d_in[13];
  const float* ln1b      = (const float*)d_in[14];
  const float* W1        = (const float*)d_in[15];
  const float* b1        = (const float*)d_in[16];
  const float* W2        = (const float*)d_in[17];
  const float* b2        = (const float*)d_in[18];
  const float* ln2s      = (const float*)d_in[19];
  const float* ln2b      = (const float*)d_in[20];
  const float* Wt        = (const float*)d_in[21];
  const float* bt        = (const float*)d_in[22];
  const float* cstart    = (const float*)d_in[23];
  const float* cend      = (const float*)d_in[24];
  const float* ctrans    = (const float*)d_in[25];

  char* w = (char*)d_ws;
  auto alloc = [&](size_t sz){ char* p = w; w += (sz + 255) & ~(size_t)255; return p; };
  u16*   xb     = (u16*)  alloc(4096ULL * 768 * 2);
  u16*   qkvb   = (u16*)  alloc(4096ULL * 2304 * 2);
  u16*   ctxb   = (u16*)  alloc(4096ULL * 768 * 2);
  u16*   tmpb   = (u16*)  alloc(4096ULL * 768 * 2);
  u16*   hb     = (u16*)  alloc(4096ULL * 3072 * 2);
  u16*   Vtb    = (u16*)  alloc(96ULL * 64 * 512 * 2);
  u16*   Wqkv_b = (u16*)  alloc(12ULL * 2304 * 768 * 2);
  u16*   Wo_b   = (u16*)  alloc(12ULL * 768 * 768 * 2);
  u16*   W1_b   = (u16*)  alloc(12ULL * 3072 * 768 * 2);
  u16*   W2_b   = (u16*)  alloc(12ULL * 768 * 3072 * 2);
  float* emis   = (float*)alloc(8ULL * 512 * 9 * 4);
  float* chunkP = (float*)alloc(8ULL * 16 * 81 * 4);
  (void)ws_size; (void)in_sizes; (void)n_in; (void)out_size;

  embed_ln<<<1024, 256, 0, stream>>>(input_ids, ttids, word_emb, pos_emb, type_emb,
                                     eln_s, eln_b, xb);
  // all-layer weight conversion up front (4 launches instead of 48)
  transcvt_l<<<dim3(72, 24, 12), 256, 0, stream>>>(Wqkv, Wqkv_b, 768, 2304);
  transcvt_l<<<dim3(24, 24, 12), 256, 0, stream>>>(Wo, Wo_b, 768, 768);
  transcvt_l<<<dim3(96, 24, 12), 256, 0, stream>>>(W1, W1_b, 768, 3072);
  transcvt_l<<<dim3(24, 96, 12), 256, 0, stream>>>(W2, W2_b, 3072, 768);

  for (int l = 0; l < 12; ++l){
    gemm_bt<0, 2><<<dim3(18, 32), 256, 0, stream>>>(xb, Wqkv_b + (size_t)l * 2304 * 768,
        bqkv + (size_t)l * 2304, qkvb, 4096, 2304, 768);
    vtrans<<<dim3(16, 2, 96), 256, 0, stream>>>(qkvb, Vtb);
    attn_fused<<<dim3(8, 12, 8), 256, 0, stream>>>(qkvb, amask, Vtb, ctxb);
    gemm_bt<0, 1><<<dim3(6, 32), 256, 0, stream>>>(ctxb, Wo_b + (size_t)l * 768 * 768,
        bo + (size_t)l * 768, tmpb, 4096, 768, 768);
    res_ln<<<1024, 256, 0, stream>>>(tmpb, xb, ln1s + (size_t)l * 768, ln1b + (size_t)l * 768, xb);
    gemm_bt<1, 2><<<dim3(24, 32), 256, 0, stream>>>(xb, W1_b + (size_t)l * 3072 * 768,
        b1 + (size_t)l * 3072, hb, 4096, 3072, 768);
    gemm_bt<0, 1><<<dim3(6, 32), 256, 0, stream>>>(hb, W2_b + (size_t)l * 768 * 3072,
        b2 + (size_t)l * 768, tmpb, 4096, 768, 3072);
    res_ln<<<1024, 256, 0, stream>>>(tmpb, xb, ln2s + (size_t)l * 768, ln2b + (size_t)l * 768, xb);
  }
  emis_k<<<1024, 256, 0, stream>>>(xb, Wt, bt, emis);
  crf_chunk<<<128, 128, 0, stream>>>(emis, amask, ctrans, chunkP);
  crf_final<<<1, 128, 0, stream>>>(emis, labels, amask, cstart, cend, ctrans, chunkP,
                                   (float*)d_out);
}

// Round 5
// 1747.082 us; speedup vs baseline: 1.5372x; 1.1603x over previous
//
#include <hip/hip_runtime.h>
#include <math.h>

typedef unsigned short u16;
typedef unsigned int u32;
typedef __bf16 bf16x8 __attribute__((ext_vector_type(8)));
typedef float f32x4 __attribute__((ext_vector_type(4)));

// ---------- helpers ----------
__device__ __forceinline__ u16 f2bf(float f){
  unsigned u = __float_as_uint(f);
  unsigned r = u + 0x7fffu + ((u >> 16) & 1u);
  return (u16)(r >> 16);
}
__device__ __forceinline__ float bf2f(u16 h){ return __uint_as_float(((unsigned)h) << 16); }

__device__ __forceinline__ void gload_lds16(const void* g, void* l){
  __builtin_amdgcn_global_load_lds(
      (__attribute__((address_space(1))) void*)(g),
      (__attribute__((address_space(3))) void*)(l), 16, 0, 0);
}
__device__ __forceinline__ f32x4 mfma16(bf16x8 a, bf16x8 b, f32x4 c){
  return __builtin_amdgcn_mfma_f32_16x16x32_bf16(a, b, c, 0, 0, 0);
}
__device__ __forceinline__ float gelu_f(float x){
  float a = 0.7978845608028654f * (x + 0.044715f * x * x * x);
  a = fminf(fmaxf(a, -15.f), 15.f);
  float t = __expf(2.f * a);
  return 0.5f * x * (1.f + (t - 1.f) / (t + 1.f));
}

// ---------- transpose + f32->bf16 convert: W[l][K][N] -> Wt[l][N][K] ----------
__global__ __launch_bounds__(256) void transcvt_l(const float* __restrict__ W,
                                                  u16* __restrict__ Wt, int K, int N){
  int l = blockIdx.z;
  W  += (size_t)l * K * N;
  Wt += (size_t)l * N * K;
  __shared__ float tile[32][33];
  int tx = threadIdx.x & 31, ty = threadIdx.x >> 5;
  int n0 = blockIdx.x * 32, k0 = blockIdx.y * 32;
  #pragma unroll
  for (int j = 0; j < 32; j += 8)
    tile[ty + j][tx] = W[(size_t)(k0 + ty + j) * N + n0 + tx];
  __syncthreads();
  #pragma unroll
  for (int j = 0; j < 32; j += 8)
    Wt[(size_t)(n0 + ty + j) * K + k0 + tx] = f2bf(tile[tx][ty + j]);
}

// ---------- embedding + layernorm -> bf16 x ----------
__global__ __launch_bounds__(256) void embed_ln(const int* __restrict__ ids,
    const int* __restrict__ tts, const float* __restrict__ we, const float* __restrict__ pe,
    const float* __restrict__ te, const float* __restrict__ g, const float* __restrict__ bb,
    u16* __restrict__ xb){
  int tok = blockIdx.x * 4 + (threadIdx.x >> 6);
  int lane = threadIdx.x & 63;
  int s = tok & 511;
  int id = ids[tok], tt = tts[tok];
  float e[12]; float sum = 0.f, sq = 0.f;
  #pragma unroll
  for (int j = 0; j < 12; ++j){
    int c = lane + j * 64;
    float v = we[(size_t)id * 768 + c] + pe[(size_t)s * 768 + c] + te[(size_t)tt * 768 + c];
    e[j] = v; sum += v; sq += v * v;
  }
  #pragma unroll
  for (int o = 1; o < 64; o <<= 1){ sum += __shfl_xor(sum, o); sq += __shfl_xor(sq, o); }
  float mean = sum * (1.f / 768.f);
  float var = sq * (1.f / 768.f) - mean * mean;
  float inv = rsqrtf(var + 1e-12f);
  size_t base = (size_t)tok * 768;
  #pragma unroll
  for (int j = 0; j < 12; ++j){
    int c = lane + j * 64;
    xb[base + c] = f2bf((e[j] - mean) * inv * g[c] + bb[c]);
  }
}

// ---------- partial-sum + bias + residual + layernorm ----------
// xout = LN(res + bias + sum_p parts[p]) ; parts are bf16 [P][4096][768]
template<int P>
__global__ __launch_bounds__(256) void res_ln_p(const u16* __restrict__ parts,
    const u16* __restrict__ res, const float* __restrict__ bias,
    const float* __restrict__ g, const float* __restrict__ bb, u16* __restrict__ xout){
  int tok = blockIdx.x * 4 + (threadIdx.x >> 6);
  int lane = threadIdx.x & 63;
  size_t base = (size_t)tok * 768;
  const size_t MN = 4096ULL * 768;
  float v[12]; float sum = 0.f, sq = 0.f;
  #pragma unroll
  for (int j = 0; j < 3; ++j){
    int c = j * 256 + lane * 4;
    ushort4 r = *(const ushort4*)(res + base + c);
    f32x4 bsv = *(const f32x4*)(bias + c);
    const u16* rp = (const u16*)&r;
    float f[4];
    #pragma unroll
    for (int e = 0; e < 4; ++e) f[e] = bf2f(rp[e]) + bsv[e];
    #pragma unroll
    for (int p = 0; p < P; ++p){
      ushort4 a = *(const ushort4*)(parts + p * MN + base + c);
      const u16* ap = (const u16*)&a;
      #pragma unroll
      for (int e = 0; e < 4; ++e) f[e] += bf2f(ap[e]);
    }
    #pragma unroll
    for (int e = 0; e < 4; ++e){
      v[j * 4 + e] = f[e]; sum += f[e]; sq += f[e] * f[e];
    }
  }
  #pragma unroll
  for (int o = 1; o < 64; o <<= 1){ sum += __shfl_xor(sum, o); sq += __shfl_xor(sq, o); }
  float mean = sum * (1.f / 768.f);
  float var = sq * (1.f / 768.f) - mean * mean;
  float inv = rsqrtf(var + 1e-12f);
  #pragma unroll
  for (int j = 0; j < 3; ++j){
    int c = j * 256 + lane * 4;
    f32x4 gs = *(const f32x4*)(g + c);
    f32x4 bs = *(const f32x4*)(bb + c);
    ushort4 o; u16* op = (u16*)&o;
    #pragma unroll
    for (int e = 0; e < 4; ++e)
      op[e] = f2bf((v[j * 4 + e] - mean) * inv * gs[e] + bs[e]);
    *(ushort4*)(xout + base + c) = o;
  }
}

// ---------- GEMM: C = A[M][K](bf16) * Bt[N][K]^T (bf16) + bias ----------
// BK=64. EPI 1: gelu -> bf16 ; EPI 3: QKV (Q,K -> Cout; V -> Cout2 transposed [bh][d][s])
// XSPLIT=2: XCDs arranged 2(bx) x 4(by); XSPLIT=1: XCDs own by-rows.
template<int EPI, int XSPLIT>
__global__ __launch_bounds__(256, 2)
void gemm_bt(const u16* __restrict__ A, const u16* __restrict__ Bt,
             const float* __restrict__ bias, void* __restrict__ Cout,
             void* __restrict__ Cout2, int M, int N, int K){
  __shared__ u16 lA[128 * 64];
  __shared__ u16 lB[128 * 64];
  const int tid = threadIdx.x, lane = tid & 63, wv = tid >> 6;
  const int wm = wv >> 1, wn = wv & 1;
  const int gx = gridDim.x, gy = gridDim.y;
  int bid = blockIdx.y * gx + blockIdx.x;
  int xcd = bid & 7, idx = bid >> 3;
  int bx, by;
  if (XSPLIT == 2){
    int cw = gx >> 1, ch = gy >> 2;
    bx = (xcd >> 2) * cw + idx % cw;
    by = (xcd & 3) * ch + idx / cw;
  } else {
    int ch = gy >> 3;
    bx = idx % gx;
    by = xcd * ch + idx / gx;
  }
  const int row0 = by * 128, col0 = bx * 128;
  f32x4 acc[4][4] = {};
  for (int k0 = 0; k0 < K; k0 += 64){
    #pragma unroll
    for (int s = 0; s < 4; ++s){
      int i = s * 256 + tid;
      int r = i >> 3, p = i & 7;
      int sk = k0 + ((p ^ (r & 7)) << 3);
      gload_lds16(A + (size_t)(row0 + r) * K + sk, (char*)lA + i * 16);
      gload_lds16(Bt + (size_t)(col0 + r) * K + sk, (char*)lB + i * 16);
    }
    __syncthreads();
    int g = lane >> 4;
    #pragma unroll
    for (int kk = 0; kk < 2; ++kk){
      bf16x8 af[4], bfv[4];
      #pragma unroll
      for (int m = 0; m < 4; ++m){
        int r = wm * 64 + m * 16 + (lane & 15);
        af[m] = *(const bf16x8*)((const char*)lA + r * 128 + (((kk * 4 + g) ^ (r & 7)) << 4));
      }
      #pragma unroll
      for (int n = 0; n < 4; ++n){
        int r = wn * 64 + n * 16 + (lane & 15);
        bfv[n] = *(const bf16x8*)((const char*)lB + r * 128 + (((kk * 4 + g) ^ (r & 7)) << 4));
      }
      #pragma unroll
      for (int m = 0; m < 4; ++m)
        #pragma unroll
        for (int n = 0; n < 4; ++n)
          acc[m][n] = mfma16(af[m], bfv[n], acc[m][n]);
    }
    __syncthreads();
  }
  if (EPI == 3 && col0 >= 1536){
    // V section: write transposed to Vt[bh][d][s]
    u16* Vt = (u16*)Cout2;
    #pragma unroll
    for (int n = 0; n < 4; ++n){
      int gc = col0 + wn * 64 + n * 16 + (lane & 15);
      float bv = bias[gc];
      int vcol = gc - 1536, hh = vcol >> 6, dd = vcol & 63;
      #pragma unroll
      for (int m = 0; m < 4; ++m){
        int gr = row0 + wm * 64 + m * 16 + (lane >> 4) * 4;
        int bbi = gr >> 9, ss = gr & 511;
        u32 w0 = (u32)f2bf(acc[m][n][0] + bv) | ((u32)f2bf(acc[m][n][1] + bv) << 16);
        u32 w1 = (u32)f2bf(acc[m][n][2] + bv) | ((u32)f2bf(acc[m][n][3] + bv) << 16);
        *(uint2*)(Vt + ((size_t)(bbi * 12 + hh) * 64 + dd) * 512 + ss) = uint2{w0, w1};
      }
    }
  } else {
    #pragma unroll
    for (int n = 0; n < 4; ++n){
      int gc = col0 + wn * 64 + n * 16 + (lane & 15);
      float bv = bias[gc];
      #pragma unroll
      for (int m = 0; m < 4; ++m){
        int gr = row0 + wm * 64 + m * 16 + (lane >> 4) * 4;
        #pragma unroll
        for (int j = 0; j < 4; ++j){
          float v = acc[m][n][j] + bv;
          if (EPI == 1) v = gelu_f(v);
          ((u16*)Cout)[(size_t)(gr + j) * N + gc] = f2bf(v);
        }
      }
    }
  }
}

// ---------- split-K GEMM: partC[z] = A * Bt^T over K-slice z (no bias) ----------
template<int KSPLIT>
__global__ __launch_bounds__(256, 2)
void gemm_bt_sk(const u16* __restrict__ A, const u16* __restrict__ Bt,
                u16* __restrict__ partC, int M, int N, int K){
  __shared__ u16 lA[128 * 64];
  __shared__ u16 lB[128 * 64];
  const int tid = threadIdx.x, lane = tid & 63, wv = tid >> 6;
  const int wm = wv >> 1, wn = wv & 1;
  const int gx = gridDim.x, gy = gridDim.y;
  int bid = blockIdx.y * gx + blockIdx.x;
  int xcd = bid & 7, idx = bid >> 3;
  int ch = gy >> 3;
  int bx = idx % gx, by = xcd * ch + idx / gx;
  const int row0 = by * 128, col0 = bx * 128;
  int z = blockIdx.z;
  int ks = K / KSPLIT;
  int kbeg = z * ks, kend = kbeg + ks;
  f32x4 acc[4][4] = {};
  for (int k0 = kbeg; k0 < kend; k0 += 64){
    #pragma unroll
    for (int s = 0; s < 4; ++s){
      int i = s * 256 + tid;
      int r = i >> 3, p = i & 7;
      int sk = k0 + ((p ^ (r & 7)) << 3);
      gload_lds16(A + (size_t)(row0 + r) * K + sk, (char*)lA + i * 16);
      gload_lds16(Bt + (size_t)(col0 + r) * K + sk, (char*)lB + i * 16);
    }
    __syncthreads();
    int g = lane >> 4;
    #pragma unroll
    for (int kk = 0; kk < 2; ++kk){
      bf16x8 af[4], bfv[4];
      #pragma unroll
      for (int m = 0; m < 4; ++m){
        int r = wm * 64 + m * 16 + (lane & 15);
        af[m] = *(const bf16x8*)((const char*)lA + r * 128 + (((kk * 4 + g) ^ (r & 7)) << 4));
      }
      #pragma unroll
      for (int n = 0; n < 4; ++n){
        int r = wn * 64 + n * 16 + (lane & 15);
        bfv[n] = *(const bf16x8*)((const char*)lB + r * 128 + (((kk * 4 + g) ^ (r & 7)) << 4));
      }
      #pragma unroll
      for (int m = 0; m < 4; ++m)
        #pragma unroll
        for (int n = 0; n < 4; ++n)
          acc[m][n] = mfma16(af[m], bfv[n], acc[m][n]);
    }
    __syncthreads();
  }
  u16* Cp = partC + (size_t)z * M * N;
  #pragma unroll
  for (int n = 0; n < 4; ++n){
    int gc = col0 + wn * 64 + n * 16 + (lane & 15);
    #pragma unroll
    for (int m = 0; m < 4; ++m){
      int gr = row0 + wm * 64 + m * 16 + (lane >> 4) * 4;
      #pragma unroll
      for (int j = 0; j < 4; ++j)
        Cp[(size_t)(gr + j) * N + gc] = f2bf(acc[m][n][j]);
    }
  }
}

// ---------- fused attention: S^T = K·Q^T, per-lane softmax, PV ----------
// XCD k owns 12 whole heads (K/V L2-resident per XCD).
__global__ __launch_bounds__(256, 2) void attn_fused(const u16* __restrict__ qkv,
    const int* __restrict__ amask, const u16* __restrict__ Vt, u16* __restrict__ ctx){
  __shared__ u16 lQ[64 * 64];
  __shared__ u16 lK[128 * 64];   // scores phase: K chunk; PV phase: per-wave P buffers
  __shared__ u16 lV[64 * 128];
  __shared__ float lbias[512];
  int i = (blockIdx.z * gridDim.y + blockIdx.y) * gridDim.x + blockIdx.x;
  int xcd = i & 7, slot = i >> 3;
  int bh = xcd * 12 + (slot >> 3);
  int q0 = (slot & 7) * 64;
  int b = bh / 12, h = bh % 12;
  int tid = threadIdx.x, lane = tid & 63, wv = tid >> 6;
  int q15 = lane & 15, g = lane >> 4;
  const size_t ld = 2304;
  const u16* base = qkv + (size_t)b * 512 * ld + (size_t)h * 64;
  #pragma unroll
  for (int s = 0; s < 2; ++s){
    int ii = s * 256 + tid, r = ii >> 3, p = ii & 7;
    gload_lds16(base + (size_t)(q0 + r) * ld + ((p ^ (r & 7)) << 3), (char*)lQ + ii * 16);
  }
  for (int ix = tid; ix < 512; ix += 256)
    lbias[ix] = (1.f - (float)amask[(size_t)b * 512 + ix]) * -1e9f;
  f32x4 acc[32];
  #pragma unroll
  for (int ii = 0; ii < 32; ++ii) acc[ii] = {};
  int mr = wv * 16 + q15;
  bf16x8 aq[2];
  #pragma unroll
  for (int c = 0; c < 4; ++c){
    #pragma unroll
    for (int s = 0; s < 4; ++s){
      int ii = s * 256 + tid, r = ii >> 3, p = ii & 7;
      gload_lds16(base + 768 + (size_t)(c * 128 + r) * ld + ((p ^ (r & 7)) << 3),
                  (char*)lK + ii * 16);
    }
    __syncthreads();
    if (c == 0){
      #pragma unroll
      for (int ks = 0; ks < 2; ++ks){
        int slog = ks * 4 + g;
        aq[ks] = *(const bf16x8*)((const char*)lQ + mr * 128 + ((slog ^ (mr & 7)) << 4));
      }
    }
    __builtin_amdgcn_s_setprio(1);
    #pragma unroll
    for (int nf = 0; nf < 8; ++nf){
      int kr = nf * 16 + q15;
      #pragma unroll
      for (int ks = 0; ks < 2; ++ks){
        int slog = ks * 4 + g;
        bf16x8 bk = *(const bf16x8*)((const char*)lK + kr * 128 + ((slog ^ (kr & 7)) << 4));
        acc[c * 8 + nf] = mfma16(bk, aq[ks], acc[c * 8 + nf]);   // C[k][q]
      }
    }
    __builtin_amdgcn_s_setprio(0);
    __syncthreads();
  }
  // per-lane softmax: lane owns q = q0+wv*16+q15, k = ii*16 + g*4 + j
  float mx = -3e38f;
  #pragma unroll
  for (int ii = 0; ii < 32; ++ii){
    f32x4 b4 = *(const f32x4*)((const char*)lbias + ii * 64 + g * 16);
    #pragma unroll
    for (int j = 0; j < 4; ++j){
      float v = acc[ii][j] * 0.125f + b4[j];
      acc[ii][j] = v; mx = fmaxf(mx, v);
    }
  }
  mx = fmaxf(mx, __shfl_xor(mx, 16));
  mx = fmaxf(mx, __shfl_xor(mx, 32));
  float sm = 0.f;
  #pragma unroll
  for (int ii = 0; ii < 32; ++ii)
    #pragma unroll
    for (int j = 0; j < 4; ++j){ float p = __expf(acc[ii][j] - mx); acc[ii][j] = p; sm += p; }
  sm += __shfl_xor(sm, 16);
  sm += __shfl_xor(sm, 32);
  float inv = 1.f / sm;
  // PV
  const u16* Vg = Vt + (size_t)(b * 12 + h) * 64 * 512;
  f32x4 accpv[4] = {};
  char* wvP = (char*)lK + wv * 4096;   // per-wave 16q x 128k bf16, XOR-swizzled
  #pragma unroll
  for (int c = 0; c < 4; ++c){
    #pragma unroll
    for (int s = 0; s < 4; ++s){
      int ii = s * 256 + tid, r = ii >> 4, p = ii & 15;
      gload_lds16(Vg + (size_t)r * 512 + c * 128 + ((p ^ (r & 7)) << 3), (char*)lV + ii * 16);
    }
    #pragma unroll
    for (int i2 = 0; i2 < 8; ++i2){
      int ii = c * 8 + i2;
      u32 w0 = (u32)f2bf(acc[ii][0] * inv) | ((u32)f2bf(acc[ii][1] * inv) << 16);
      u32 w1 = (u32)f2bf(acc[ii][2] * inv) | ((u32)f2bf(acc[ii][3] * inv) << 16);
      int slotp = i2 * 2 + (g >> 1);
      char* ad = wvP + q15 * 256 + ((slotp ^ (q15 & 7)) << 4) + ((g & 1) << 3);
      *(uint2*)ad = uint2{w0, w1};
    }
    __syncthreads();
    __builtin_amdgcn_s_setprio(1);
    #pragma unroll
    for (int s = 0; s < 4; ++s){
      bf16x8 pa = *(const bf16x8*)(wvP + q15 * 256 + (((s * 4 + g) ^ (q15 & 7)) << 4));
      #pragma unroll
      for (int nf = 0; nf < 4; ++nf){
        int dr = nf * 16 + q15;
        bf16x8 bv = *(const bf16x8*)((const char*)lV + dr * 256 + (((s * 4 + g) ^ (dr & 7)) << 4));
        accpv[nf] = mfma16(pa, bv, accpv[nf]);
      }
    }
    __builtin_amdgcn_s_setprio(0);
    __syncthreads();
  }
  u16* C = ctx + (size_t)b * 512 * 768 + (size_t)h * 64;
  #pragma unroll
  for (int nf = 0; nf < 4; ++nf)
    #pragma unroll
    for (int j = 0; j < 4; ++j){
      int q = q0 + wv * 16 + g * 4 + j;
      int d = nf * 16 + q15;
      C[(size_t)q * 768 + d] = f2bf(accpv[nf][j]);
    }
}

// ---------- emissions: x @ Wt(768x9 f32) + bt -> f32 ----------
__global__ __launch_bounds__(256) void emis_k(const u16* __restrict__ xb,
    const float* __restrict__ Wt, const float* __restrict__ bt, float* __restrict__ emis){
  int row = blockIdx.x * 4 + (threadIdx.x >> 6);
  int lane = threadIdx.x & 63;
  float a[9] = {};
  #pragma unroll
  for (int j = 0; j < 12; ++j){
    int k = lane + j * 64;
    float xv = bf2f(xb[(size_t)row * 768 + k]);
    #pragma unroll
    for (int t = 0; t < 9; ++t) a[t] += xv * Wt[(size_t)k * 9 + t];
  }
  #pragma unroll
  for (int o = 1; o < 64; o <<= 1)
    #pragma unroll
    for (int t = 0; t < 9; ++t) a[t] += __shfl_xor(a[t], o);
  if (lane == 0){
    #pragma unroll
    for (int t = 0; t < 9; ++t) emis[(size_t)row * 9 + t] = a[t] + bt[t];
  }
}

// ---------- CRF chunk products: log-semiring 9x9 matrix scan ----------
__global__ __launch_bounds__(128) void crf_chunk(const float* __restrict__ emis,
    const int* __restrict__ amask, const float* __restrict__ ctrans,
    float* __restrict__ chunkP){
  __shared__ float cur[2][96];
  int blk = blockIdx.x; int b = blk >> 4, c = blk & 15;
  int t0 = threadIdx.x;
  bool act = t0 < 81;
  int tc = act ? t0 : 0;
  int i = tc / 9, j = tc - i * 9;
  float tr[9];
  #pragma unroll
  for (int k = 0; k < 9; ++k) tr[k] = ctrans[k * 9 + j];
  const float* eb = emis + (size_t)b * 512 * 9;
  const int* mb = amask + (size_t)b * 512;
  int lo = c * 32 + (c == 0 ? 1 : 0), hi = c * 32 + 31;
  if (act){
    int m = mb[lo];
    cur[0][t0] = m ? (ctrans[i * 9 + j] + eb[(size_t)lo * 9 + j])
                   : (i == j ? 0.f : -1e30f);
  }
  __syncthreads();
  int pp = 0;
  for (int t = lo + 1; t <= hi; ++t){
    float a[9];
    #pragma unroll
    for (int k = 0; k < 9; ++k) a[k] = cur[pp][i * 9 + k];
    int m = mb[t];
    float outv;
    if (m){
      float ej = eb[(size_t)t * 9 + j];
      float mm = -3e38f;
      #pragma unroll
      for (int k = 0; k < 9; ++k){ a[k] += tr[k]; mm = fmaxf(mm, a[k]); }
      float ss = 0.f;
      #pragma unroll
      for (int k = 0; k < 9; ++k) ss += __expf(a[k] - mm);
      outv = ej + mm + __logf(ss);
    } else {
      outv = a[j];
    }
    if (act) cur[pp ^ 1][t0] = outv;
    __syncthreads();
    pp ^= 1;
  }
  if (act) chunkP[(size_t)(b * 16 + c) * 81 + t0] = cur[pp][t0];
}

// ---------- CRF final: numerator + apply chunk products + combine ----------
__global__ __launch_bounds__(128) void crf_final(const float* __restrict__ emis,
    const int* __restrict__ labels, const int* __restrict__ amask,
    const float* __restrict__ cstart, const float* __restrict__ cend,
    const float* __restrict__ ctrans, const float* __restrict__ chunkP,
    float* __restrict__ out){
  __shared__ float numb[8], denb[8];
  int tid = threadIdx.x;
  { // numerator
    int b = tid >> 4, gg = tid & 15;
    const int* lab = labels + (size_t)b * 512;
    const int* msk = amask + (size_t)b * 512;
    float part = 0.f; int cnt = 0;
    for (int i = gg; i < 512; i += 16){
      int m = msk[i]; cnt += m;
      if (i >= 1){
        int tp = lab[i - 1], tcc = lab[i];
        part += (ctrans[tp * 9 + tcc] + emis[((size_t)b * 512 + i) * 9 + tcc]) * (float)m;
      }
    }
    #pragma unroll
    for (int o = 1; o < 16; o <<= 1){ part += __shfl_xor(part, o); cnt += __shfl_xor(cnt, o); }
    if (gg == 0){
      int tt0 = lab[0];
      numb[b] = part + cstart[tt0] + emis[((size_t)b * 512) * 9 + tt0] + cend[lab[cnt - 1]];
    }
  }
  __syncthreads();
  { // denominator via 16 chunk products
    int lane = tid & 63, w = tid >> 6;
    int sub = lane >> 4, j = lane & 15;
    int b = w * 4 + sub;
    bool act = j < 9;
    int jj = act ? j : 0;
    int gbase = lane & 48;
    float alpha = cstart[jj] + emis[(size_t)b * 512 * 9 + jj];
    for (int c = 0; c < 16; ++c){
      const float* P = chunkP + (size_t)(b * 16 + c) * 81;
      float av[9];
      #pragma unroll
      for (int k = 0; k < 9; ++k) av[k] = __shfl(alpha, gbase + k) + P[k * 9 + jj];
      float mm = -3e38f;
      #pragma unroll
      for (int k = 0; k < 9; ++k) mm = fmaxf(mm, av[k]);
      float ss = 0.f;
      #pragma unroll
      for (int k = 0; k < 9; ++k) ss += __expf(av[k] - mm);
      alpha = mm + __logf(ss);
    }
    float v = alpha + cend[jj];
    float av[9];
    #pragma unroll
    for (int k = 0; k < 9; ++k) av[k] = __shfl(v, gbase + k);
    float mm = -3e38f;
    #pragma unroll
    for (int k = 0; k < 9; ++k) mm = fmaxf(mm, av[k]);
    float ss = 0.f;
    #pragma unroll
    for (int k = 0; k < 9; ++k) ss += __expf(av[k] - mm);
    if (act && j == 0) denb[b] = mm + __logf(ss);
  }
  __syncthreads();
  if (tid == 0){
    float s = 0.f;
    #pragma unroll
    for (int b = 0; b < 8; ++b) s += numb[b] - denb[b];
    out[0] = -(s * 0.125f);
  }
}

// ---------- host ----------
extern "C" void kernel_launch(void* const* d_in, const int* in_sizes, int n_in,
                              void* d_out, int out_size, void* d_ws, size_t ws_size,
                              hipStream_t stream){
  const int*   input_ids = (const int*)d_in[0];
  const int*   amask     = (const int*)d_in[1];
  const int*   ttids     = (const int*)d_in[2];
  const int*   labels    = (const int*)d_in[3];
  const float* word_emb  = (const float*)d_in[4];
  const float* pos_emb   = (const float*)d_in[5];
  const float* type_emb  = (const float*)d_in[6];
  const float* eln_s     = (const float*)d_in[7];
  const float* eln_b     = (const float*)d_in[8];
  const float* Wqkv      = (const float*)d_in[9];
  const float* bqkv      = (const float*)d_in[10];
  const float* Wo        = (const float*)d_in[11];
  const float* bo        = (const float*)d_in[12];
  const float* ln1s      = (const float*)d_in[13];
  const float* ln1b      = (const float*)d_in[14];
  const float* W1        = (const float*)d_in[15];
  const float* b1        = (const float*)d_in[16];
  const float* W2        = (const float*)d_in[17];
  const float* b2        = (const float*)d_in[18];
  const float* ln2s      = (const float*)d_in[19];
  const float* ln2b      = (const float*)d_in[20];
  const float* Wt        = (const float*)d_in[21];
  const float* bt        = (const float*)d_in[22];
  const float* cstart    = (const float*)d_in[23];
  const float* cend      = (const float*)d_in[24];
  const float* ctrans    = (const float*)d_in[25];

  char* w = (char*)d_ws;
  auto alloc = [&](size_t sz){ char* p = w; w += (sz + 255) & ~(size_t)255; return p; };
  u16*   xb     = (u16*)  alloc(4096ULL * 768 * 2);
  u16*   qkvb   = (u16*)  alloc(4096ULL * 2304 * 2);
  u16*   ctxb   = (u16*)  alloc(4096ULL * 768 * 2);
  u16*   hb     = (u16*)  alloc(4096ULL * 3072 * 2);
  u16*   Vtb    = (u16*)  alloc(96ULL * 64 * 512 * 2);
  u16*   pbuf   = (u16*)  alloc(4ULL * 4096 * 768 * 2);
  u16*   Wqkv_b = (u16*)  alloc(12ULL * 2304 * 768 * 2);
  u16*   Wo_b   = (u16*)  alloc(12ULL * 768 * 768 * 2);
  u16*   W1_b   = (u16*)  alloc(12ULL * 3072 * 768 * 2);
  u16*   W2_b   = (u16*)  alloc(12ULL * 768 * 3072 * 2);
  float* emis   = (float*)alloc(8ULL * 512 * 9 * 4);
  float* chunkP = (float*)alloc(8ULL * 16 * 81 * 4);
  (void)ws_size; (void)in_sizes; (void)n_in; (void)out_size;

  embed_ln<<<1024, 256, 0, stream>>>(input_ids, ttids, word_emb, pos_emb, type_emb,
                                     eln_s, eln_b, xb);
  // all-layer weight conversion up front
  transcvt_l<<<dim3(72, 24, 12), 256, 0, stream>>>(Wqkv, Wqkv_b, 768, 2304);
  transcvt_l<<<dim3(24, 24, 12), 256, 0, stream>>>(Wo, Wo_b, 768, 768);
  transcvt_l<<<dim3(96, 24, 12), 256, 0, stream>>>(W1, W1_b, 768, 3072);
  transcvt_l<<<dim3(24, 96, 12), 256, 0, stream>>>(W2, W2_b, 3072, 768);

  for (int l = 0; l < 12; ++l){
    gemm_bt<3, 2><<<dim3(18, 32), 256, 0, stream>>>(xb, Wqkv_b + (size_t)l * 2304 * 768,
        bqkv + (size_t)l * 2304, qkvb, Vtb, 4096, 2304, 768);
    attn_fused<<<dim3(8, 12, 8), 256, 0, stream>>>(qkvb, amask, Vtb, ctxb);
    gemm_bt_sk<2><<<dim3(6, 32, 2), 256, 0, stream>>>(ctxb, Wo_b + (size_t)l * 768 * 768,
        pbuf, 4096, 768, 768);
    res_ln_p<2><<<1024, 256, 0, stream>>>(pbuf, xb, bo + (size_t)l * 768,
        ln1s + (size_t)l * 768, ln1b + (size_t)l * 768, xb);
    gemm_bt<1, 2><<<dim3(24, 32), 256, 0, stream>>>(xb, W1_b + (size_t)l * 3072 * 768,
        b1 + (size_t)l * 3072, hb, nullptr, 4096, 3072, 768);
    gemm_bt_sk<4><<<dim3(6, 32, 4), 256, 0, stream>>>(hb, W2_b + (size_t)l * 768 * 3072,
        pbuf, 4096, 768, 3072);
    res_ln_p<4><<<1024, 256, 0, stream>>>(pbuf, xb, b2 + (size_t)l * 768,
        ln2s + (size_t)l * 768, ln2b + (size_t)l * 768, xb);
  }
  emis_k<<<1024, 256, 0, stream>>>(xb, Wt, bt, emis);
  crf_chunk<<<128, 128, 0, stream>>>(emis, amask, ctrans, chunkP);
  crf_final<<<1, 128, 0, stream>>>(emis, labels, amask, cstart, cend, ctrans, chunkP,
                                   (float*)d_out);
}